// Round 2
// baseline (1068.823 us; speedup 1.0000x reference)
//
#include <hip/hip_runtime.h>

typedef unsigned short u16;

constexpr int NN   = 50000;   // nodes
constexpr int NE   = 800000;  // edges
constexpr int TBLN = 8192;    // temporal table resolution

// ---------- helpers ----------
__device__ __forceinline__ u16 f2b(float f) {
  unsigned u = __float_as_uint(f);
  unsigned r = u + 0x7fffu + ((u >> 16) & 1u);  // RNE
  return (u16)(r >> 16);
}
template <int F32>
__device__ __forceinline__ float LD(const void* p, int i) {
  if (F32) return ((const float*)p)[i];
  return __uint_as_float(((unsigned)((const u16*)p)[i]) << 16);
}
__device__ __forceinline__ float wred64(float v) {
#pragma unroll
  for (int o = 32; o; o >>= 1) v += __shfl_xor(v, o);
  return v;
}
__device__ __forceinline__ int wred64i(int v) {
#pragma unroll
  for (int o = 32; o; o >>= 1) v += __shfl_xor(v, o);
  return v;
}

// ---------- dtype detection: are the float inputs fp32 or bf16? ----------
// If x is bf16, even-index u16s are bf16 of N(0,1) samples: exponent in ~[100,140].
// If x is fp32, even-index u16s are the LOW halves of floats: mantissa junk,
// exponent field ~uniform in [0,255] -> mostly "wild".
__global__ void detect_k(const u16* __restrict__ x, int* __restrict__ flag) {
  const int t = threadIdx.x;  // 256
  int wild = 0;
  for (int r = 0; r < 8; ++r) {
    unsigned v = x[(t * 8 + r) * 2];
    unsigned e = (v >> 7) & 0xffu;
    if (e < 100u || e > 140u) wild++;
  }
  wild = wred64i(wild);
  __shared__ int wsum[4];
  if ((t & 63) == 0) wsum[t >> 6] = wild;
  __syncthreads();
  if (t == 0) *flag = (wsum[0] + wsum[1] + wsum[2] + wsum[3] > 512) ? 1 : 0;
}

// ---------- fold edge-attention vectors: V[k][0..3]=layer1, V[k][4..7]=layer2 ----------
template <int F32>
__device__ void bV_body(const void* ew1, const void* ate1, const void* ew2,
                        const void* ate2, float* V) {
  const int t = threadIdx.x;  // 256
#pragma unroll
  for (int rep = 0; rep < 2; ++rep) {
    int idx = t + rep * 256;
    int k = idx >> 2, hd = idx & 3;
    float s1 = 0.f, s2 = 0.f;
    for (int c = 0; c < 32; ++c) {
      s1 += LD<F32>(ew1, k * 128 + hd * 32 + c) * LD<F32>(ate1, hd * 32 + c);
      s2 += LD<F32>(ew2, k * 128 + hd * 32 + c) * LD<F32>(ate2, hd * 32 + c);
    }
    V[k * 8 + hd] = s1;
    V[k * 8 + 4 + hd] = s2;
  }
}
__global__ void build_V(const void* ew1, const void* ate1, const void* ew2,
                        const void* ate2, float* V, const int* flag) {
  if (*flag) bV_body<1>(ew1, ate1, ew2, ate2, V);
  else       bV_body<0>(ew1, ate1, ew2, ate2, V);
}

// ---------- tabulate a_edge(t): exact temporal MLP at TBLN grid points ----------
template <int F32>
__device__ void bT_body(const void* taw1, const void* tab1, const void* talnw,
                        const void* talnb, const void* taw2, const void* tab2,
                        const float* V, float* tbl,
                        float* part, float* ush, float* pacc) {
  const int j = threadIdx.x;
  const int wv = j >> 6, ln = j & 63;
  const float t = (float)blockIdx.x / (float)(TBLN - 1);
  float v = t * LD<F32>(taw1, j) + LD<F32>(tab1, j);
  float s = wred64(v), sq = wred64(v * v);
  if (ln == 0) { part[wv * 2] = s; part[wv * 2 + 1] = sq; }
  __syncthreads();
  float S = part[0] + part[2], SQ = part[1] + part[3];
  float mu = S * (1.f / 128.f);
  float var = SQ * (1.f / 128.f) - mu * mu;
  float rstd = rsqrtf(var + 1e-5f);
  float u = fmaxf((v - mu) * rstd * LD<F32>(talnw, j) + LD<F32>(talnb, j), 0.f);
  ush[j] = u;
  __syncthreads();
  float acc = 0.f;
  for (int k = 0; k < 128; ++k) acc += ush[k] * LD<F32>(taw2, k * 128 + j);
  float w = tanhf(acc + LD<F32>(tab2, j));
  w = fminf(fmaxf(w, -3.f), 3.f);
#pragma unroll
  for (int p = 0; p < 8; ++p) {
    float z = wred64(w * V[j * 8 + p]);
    if (ln == 0) pacc[wv * 8 + p] = z;
  }
  __syncthreads();
  if (j < 8) tbl[blockIdx.x * 8 + j] = pacc[j] + pacc[8 + j];
}
__global__ __launch_bounds__(128) void build_table(
    const void* taw1, const void* tab1, const void* talnw, const void* talnb,
    const void* taw2, const void* tab2, const float* V, float* tbl,
    const int* flag) {
  __shared__ float part[4];
  __shared__ float ush[128];
  __shared__ float pacc[16];
  if (*flag) bT_body<1>(taw1, tab1, talnw, talnb, taw2, tab2, V, tbl, part, ush, pacc);
  else       bT_body<0>(taw1, tab1, talnw, talnb, taw2, tab2, V, tbl, part, ush, pacc);
}

// ---------- input projection ----------
template <int F32>
__device__ void ip_body(const void* x, const void* w1, const void* b1,
                        const void* ln1w, const void* ln1b, const void* w2,
                        const void* b2, const void* pnw, const void* pnb,
                        float* hout, float (*xr)[128], float (*h1)[256],
                        float (*hb)[128], float (*red)[2]) {
  const int t = threadIdx.x;
  const int nb = blockIdx.x * 4;
#pragma unroll
  for (int i = 0; i < 2; ++i) {
    int idx = t + i * 256;
    xr[idx >> 7][idx & 127] = LD<F32>(x, (nb + (idx >> 7)) * 128 + (idx & 127));
  }
  __syncthreads();
  {
    float a0 = 0, a1 = 0, a2 = 0, a3 = 0;
    for (int k = 0; k < 128; ++k) {
      float w = LD<F32>(w1, k * 256 + t);
      a0 += xr[0][k] * w; a1 += xr[1][k] * w;
      a2 += xr[2][k] * w; a3 += xr[3][k] * w;
    }
    float bb = LD<F32>(b1, t);
    h1[0][t] = fmaxf(a0 + bb, 0.f);
    h1[1][t] = fmaxf(a1 + bb, 0.f);
    h1[2][t] = fmaxf(a2 + bb, 0.f);
    h1[3][t] = fmaxf(a3 + bb, 0.f);
  }
  __syncthreads();
  const int wv = t >> 6, ln = t & 63;
  {
    float a = h1[wv][ln], b = h1[wv][ln + 64];
    float c = h1[wv][ln + 128], d = h1[wv][ln + 192];
    float s = wred64(a + b + c + d);
    float sq = wred64(a * a + b * b + c * c + d * d);
    if (ln == 0) {
      float mu = s * (1.f / 256.f);
      float var = sq * (1.f / 256.f) - mu * mu;
      red[wv][0] = mu;
      red[wv][1] = rsqrtf(var + 1e-5f);
    }
  }
  __syncthreads();
  {
    float lw = LD<F32>(ln1w, t), lb = LD<F32>(ln1b, t);
#pragma unroll
    for (int i = 0; i < 4; ++i)
      h1[i][t] = (h1[i][t] - red[i][0]) * red[i][1] * lw + lb;
  }
  __syncthreads();
#pragma unroll
  for (int rep = 0; rep < 2; ++rep) {
    int idx = t + rep * 256;
    int i = idx >> 7, j = idx & 127;
    float acc = 0.f;
    for (int k = 0; k < 256; ++k) acc += h1[i][k] * LD<F32>(w2, k * 128 + j);
    hb[i][j] = acc + LD<F32>(b2, j);
  }
  __syncthreads();
  {
    float v0 = hb[wv][ln], v1 = hb[wv][ln + 64];
    float s = wred64(v0 + v1);
    float sq = wred64(v0 * v0 + v1 * v1);
    float mu = s * (1.f / 128.f);
    float var = sq * (1.f / 128.f) - mu * mu;
    float rstd = rsqrtf(var + 1e-5f);
    float y0 = (v0 - mu) * rstd * LD<F32>(pnw, ln) + LD<F32>(pnb, ln);
    float y1 = (v1 - mu) * rstd * LD<F32>(pnw, ln + 64) + LD<F32>(pnb, ln + 64);
    y0 = fminf(fmaxf(y0, 0.f), 10.f);
    y1 = fminf(fmaxf(y1, 0.f), 10.f);
    hout[(nb + wv) * 128 + ln] = y0;
    hout[(nb + wv) * 128 + ln + 64] = y1;
  }
}
__global__ __launch_bounds__(256) void input_proj(
    const void* x, const void* w1, const void* b1, const void* ln1w,
    const void* ln1b, const void* w2, const void* b2, const void* pnw,
    const void* pnb, float* hout, const int* flag) {
  __shared__ float xr[4][128];
  __shared__ float h1[4][256];
  __shared__ float hb[4][128];
  __shared__ float red[4][2];
  if (*flag) ip_body<1>(x, w1, b1, ln1w, ln1b, w2, b2, pnw, pnb, hout, xr, h1, hb, red);
  else       ip_body<0>(x, w1, b1, ln1w, ln1b, w2, b2, pnw, pnb, hout, xr, h1, hb, red);
}

// ---------- per-edge: table lookup -> a_edge (both layers) + deg histogram ----------
template <int F32>
__device__ void ea_body(const void* etime, const int* __restrict__ dstv,
                        const float* __restrict__ tbl, float4* ae1, float4* ae2,
                        int* deg) {
  const int e = blockIdx.x * 256 + threadIdx.x;
  if (e >= NE) return;
  float t = LD<F32>(etime, e);
  t = fminf(fmaxf(t, 0.f), 1.f);
  float pos = t * (float)(TBLN - 1);
  int i0 = (int)pos;
  if (i0 > TBLN - 2) i0 = TBLN - 2;
  float fr = pos - (float)i0;
  const float4* r = (const float4*)(tbl + i0 * 8);
  float4 a0 = r[0], a1 = r[1], b0 = r[2], b1 = r[3];
  float4 o1, o2;
  o1.x = a0.x + fr * (b0.x - a0.x);
  o1.y = a0.y + fr * (b0.y - a0.y);
  o1.z = a0.z + fr * (b0.z - a0.z);
  o1.w = a0.w + fr * (b0.w - a0.w);
  o2.x = a1.x + fr * (b1.x - a1.x);
  o2.y = a1.y + fr * (b1.y - a1.y);
  o2.z = a1.z + fr * (b1.z - a1.z);
  o2.w = a1.w + fr * (b1.w - a1.w);
  ae1[e] = o1;
  ae2[e] = o2;
  atomicAdd(&deg[dstv[e]], 1);
}
__global__ __launch_bounds__(256) void edge_apply(
    const void* etime, const int* dstv, const float* tbl, float4* ae1,
    float4* ae2, int* deg, const int* flag) {
  if (*flag) ea_body<1>(etime, dstv, tbl, ae1, ae2, deg);
  else       ea_body<0>(etime, dstv, tbl, ae1, ae2, deg);
}

// ---------- CSR build: scan (3 kernels) + fill ----------
__global__ __launch_bounds__(512) void scan1(const int* __restrict__ deg,
                                             int* __restrict__ indptr,
                                             int* __restrict__ blks) {
  const int t = threadIdx.x;
  const int i = blockIdx.x * 512 + t;
  int v = (i < NN) ? deg[i] : 0;
  const int lane = t & 63, wv = t >> 6;
  int x = v;
#pragma unroll
  for (int o = 1; o < 64; o <<= 1) {
    int y = __shfl_up(x, o);
    if (lane >= o) x += y;
  }
  __shared__ int ws[8];
  if (lane == 63) ws[wv] = x;
  __syncthreads();
  if (t < 8) {
    int y = ws[t];
#pragma unroll
    for (int o = 1; o < 8; o <<= 1) {
      int z = __shfl_up(y, o);
      if (t >= o) y += z;
    }
    ws[t] = y;
  }
  __syncthreads();
  int excl = wv ? ws[wv - 1] : 0;
  x += excl;
  if (i < NN) indptr[i + 1] = x;
  if (t == 511) blks[blockIdx.x] = x;
}

__global__ void scan2(int* __restrict__ blks, int nb) {
  const int t = threadIdx.x;  // 128 threads
  int v = (t < nb) ? blks[t] : 0;
  const int lane = t & 63, wv = t >> 6;
  int x = v;
#pragma unroll
  for (int o = 1; o < 64; o <<= 1) {
    int y = __shfl_up(x, o);
    if (lane >= o) x += y;
  }
  __shared__ int ws[2];
  if (lane == 63) ws[wv] = x;
  __syncthreads();
  if (wv == 1) x += ws[0];
  if (t < nb) blks[t] = x - v;  // exclusive
}

__global__ __launch_bounds__(512) void scan3(int* __restrict__ indptr,
                                             const int* __restrict__ blks) {
  const int i = blockIdx.x * 512 + threadIdx.x;
  if (i < NN) indptr[i + 1] += blks[blockIdx.x];
  if (i == 0) indptr[0] = 0;
}

__global__ __launch_bounds__(256) void fill_csr(const int* __restrict__ dstv,
                                                const int* __restrict__ indptr,
                                                int* __restrict__ cursor,
                                                int* __restrict__ csr) {
  const int e = blockIdx.x * 256 + threadIdx.x;
  if (e >= NE) return;
  int d = dstv[e];
  int p = atomicAdd(&cursor[d], 1);
  csr[indptr[d] + p] = e;
}

// ---------- hproj = feat @ W, plus a_src/a_dst ----------
template <int F32>
__device__ void hp_body(const float* __restrict__ feat, const void* W,
                        const void* attsrc, const void* attdst, float* hp,
                        float* asrc, float* adst, float (*fr)[128]) {
  const int t = threadIdx.x;
  const int nb = blockIdx.x * 2;
  const int i = t >> 7, j = t & 127;
  fr[i][j] = feat[(nb + i) * 128 + j];
  __syncthreads();
  float acc = 0.f;
  for (int k = 0; k < 128; ++k) acc += fr[i][k] * LD<F32>(W, k * 128 + j);
  const int node = nb + i;
  hp[node * 128 + j] = acc;
  const int hd = j >> 5, c = j & 31;
  float vs = acc * LD<F32>(attsrc, hd * 32 + c);
  float vd = acc * LD<F32>(attdst, hd * 32 + c);
#pragma unroll
  for (int o = 16; o; o >>= 1) {
    vs += __shfl_xor(vs, o);
    vd += __shfl_xor(vd, o);
  }
  if (c == 0) {
    asrc[node * 4 + hd] = vs;
    adst[node * 4 + hd] = vd;
  }
}
__global__ __launch_bounds__(256) void hproj_k(
    const float* feat, const void* W, const void* attsrc, const void* attdst,
    float* hp, float* asrc, float* adst, const int* flag) {
  __shared__ float fr[2][128];
  if (*flag) hp_body<1>(feat, W, attsrc, attdst, hp, asrc, adst, fr);
  else       hp_body<0>(feat, W, attsrc, attdst, hp, asrc, adst, fr);
}

// ---------- GAT aggregation: one wave per node ----------
template <int FINAL, int F32>
__device__ void agg_body(
    const int* __restrict__ indptr, const int* __restrict__ csr,
    const int* __restrict__ srcv, const float* __restrict__ ae,
    const float* __restrict__ asrc, const float* __restrict__ adst,
    const float* __restrict__ hp, const float* featin, const void* gbias,
    const void* lnw, const void* lnb, float* gout, void* bout) {
  const int wv = threadIdx.x >> 6, lane = threadIdx.x & 63;
  const int n = blockIdx.x * 4 + wv;
  if (n >= NN) return;
  const int s0 = indptr[n], s1 = indptr[n + 1];
  const int dg = s1 - s0;
  const float4 adv = *(const float4*)(adst + n * 4);
  const float ad[4] = {adv.x, adv.y, adv.z, adv.w};
  float m[4] = {-INFINITY, -INFINITY, -INFINITY, -INFINITY};
  float ss[4] = {0.f, 0.f, 0.f, 0.f};
  float sa[4] = {0.f, 0.f, 0.f, 0.f};
  for (int base = s0; base < s1; base += 64) {
    int idx = base + lane;
    if (idx < s1) {
      int e = csr[idx];
      int sc = srcv[e];
      float4 as = *(const float4*)(asrc + sc * 4);
      float4 av = *(const float4*)(ae + (size_t)e * 4);
      float l[4] = {as.x + ad[0] + av.x, as.y + ad[1] + av.y,
                    as.z + ad[2] + av.z, as.w + ad[3] + av.w};
      float avv[4] = {av.x, av.y, av.z, av.w};
#pragma unroll
      for (int h = 0; h < 4; ++h) {
        float lv = fmaxf(l[h], 0.2f * l[h]);
        float mn = fmaxf(m[h], lv);
        ss[h] = ss[h] * __expf(m[h] - mn) + __expf(lv - mn);
        m[h] = mn;
        sa[h] += avv[h];
      }
    }
  }
#pragma unroll
  for (int o = 32; o; o >>= 1) {
#pragma unroll
    for (int h = 0; h < 4; ++h) {
      float mo = __shfl_xor(m[h], o);
      float so = __shfl_xor(ss[h], o);
      float ao = __shfl_xor(sa[h], o);
      float mn = fmaxf(m[h], mo);
      float t1 = ss[h] > 0.f ? ss[h] * __expf(m[h] - mn) : 0.f;
      float t2 = so > 0.f ? so * __expf(mo - mn) : 0.f;
      m[h] = mn;
      ss[h] = t1 + t2;
      sa[h] += ao;
    }
  }
  const float degf = (float)(dg > 0 ? dg : 1);
  const float4 asnv = *(const float4*)(asrc + n * 4);
  const float asn[4] = {asnv.x, asnv.y, asnv.z, asnv.w};
  float rs[4], aself[4];
#pragma unroll
  for (int h = 0; h < 4; ++h) {
    float la = asn[h] + ad[h] + sa[h] / degf;
    la = fmaxf(la, 0.2f * la);
    float mn = fmaxf(m[h], la);
    float t1 = ss[h] > 0.f ? ss[h] * __expf(m[h] - mn) : 0.f;
    ss[h] = t1 + __expf(la - mn);
    m[h] = mn;
    rs[h] = 1.f / (ss[h] + 1e-16f);
    aself[h] = __expf(la - m[h]) * rs[h];
  }
  const int hh = lane >> 5;
  const float mA = hh ? m[1] : m[0], rA = hh ? rs[1] : rs[0];
  const float mB = hh ? m[3] : m[2], rB = hh ? rs[3] : rs[2];
  const float adA = hh ? ad[1] : ad[0], adB = hh ? ad[3] : ad[2];
  const int hA = hh, hB = 2 + hh;
  const int ch0 = lane, ch1 = lane + 64;
  float acc0 = (hh ? aself[1] : aself[0]) * hp[(size_t)n * 128 + ch0];
  float acc1 = (hh ? aself[3] : aself[2]) * hp[(size_t)n * 128 + ch1];
  for (int j = s0; j < s1; ++j) {
    int e = csr[j];
    int sc = srcv[e];
    float lA = asrc[sc * 4 + hA] + adA + ae[(size_t)e * 4 + hA];
    float lB = asrc[sc * 4 + hB] + adB + ae[(size_t)e * 4 + hB];
    lA = fmaxf(lA, 0.2f * lA);
    lB = fmaxf(lB, 0.2f * lB);
    float wA = __expf(lA - mA) * rA;
    float wB = __expf(lB - mB) * rB;
    acc0 += wA * hp[(size_t)sc * 128 + ch0];
    acc1 += wB * hp[(size_t)sc * 128 + ch1];
  }
  float v0 = acc0 + LD<F32>(gbias, ch0) + featin[(size_t)n * 128 + ch0];
  float v1 = acc1 + LD<F32>(gbias, ch1) + featin[(size_t)n * 128 + ch1];
  v0 = fminf(fmaxf(v0, -10.f), 10.f);
  v1 = fminf(fmaxf(v1, -10.f), 10.f);
  float s = wred64(v0 + v1);
  float sq = wred64(v0 * v0 + v1 * v1);
  float mu = s * (1.f / 128.f);
  float var = sq * (1.f / 128.f) - mu * mu;
  float rstd = rsqrtf(var + 1e-5f);
  float y0 = (v0 - mu) * rstd * LD<F32>(lnw, ch0) + LD<F32>(lnb, ch0);
  float y1 = (v1 - mu) * rstd * LD<F32>(lnw, ch1) + LD<F32>(lnb, ch1);
  y0 = y0 > 0.f ? y0 : expm1f(y0);
  y1 = y1 > 0.f ? y1 : expm1f(y1);
  if (FINAL) {
    if (F32) {
      ((float*)bout)[(size_t)n * 128 + ch0] = y0;
      ((float*)bout)[(size_t)n * 128 + ch1] = y1;
    } else {
      ((u16*)bout)[(size_t)n * 128 + ch0] = f2b(y0);
      ((u16*)bout)[(size_t)n * 128 + ch1] = f2b(y1);
    }
  } else {
    gout[(size_t)n * 128 + ch0] = y0;
    gout[(size_t)n * 128 + ch1] = y1;
  }
}
template <int FINAL>
__global__ __launch_bounds__(256) void agg_k(
    const int* indptr, const int* csr, const int* srcv, const float* ae,
    const float* asrc, const float* adst, const float* hp, const float* featin,
    const void* gbias, const void* lnw, const void* lnb, float* gout,
    void* bout, const int* flag) {
  if (*flag)
    agg_body<FINAL, 1>(indptr, csr, srcv, ae, asrc, adst, hp, featin, gbias,
                       lnw, lnb, gout, bout);
  else
    agg_body<FINAL, 0>(indptr, csr, srcv, ae, asrc, adst, hp, featin, gbias,
                       lnw, lnb, gout, bout);
}

// ---------- launch ----------
extern "C" void kernel_launch(void* const* d_in, const int* in_sizes, int n_in,
                              void* d_out, int out_size, void* d_ws, size_t ws_size,
                              hipStream_t stream) {
  const void* x      = d_in[0];
  const void* etime  = d_in[1];
  const void* ip_w1  = d_in[2];
  const void* ip_b1  = d_in[3];
  const void* ip_lnw = d_in[4];
  const void* ip_lnb = d_in[5];
  const void* ip_w2  = d_in[6];
  const void* ip_b2  = d_in[7];
  const void* pn_w   = d_in[8];
  const void* pn_b   = d_in[9];
  const void* ta_w1  = d_in[10];
  const void* ta_b1  = d_in[11];
  const void* ta_lnw = d_in[12];
  const void* ta_lnb = d_in[13];
  const void* ta_w2  = d_in[14];
  const void* ta_b2  = d_in[15];
  const void* g1_w   = d_in[16];
  const void* g1_as  = d_in[17];
  const void* g1_ad  = d_in[18];
  const void* g1_ew  = d_in[19];
  const void* g1_ae  = d_in[20];
  const void* g1_b   = d_in[21];
  const void* g2_w   = d_in[22];
  const void* g2_as  = d_in[23];
  const void* g2_ad  = d_in[24];
  const void* g2_ew  = d_in[25];
  const void* g2_ae  = d_in[26];
  const void* g2_b   = d_in[27];
  const void* n1_w   = d_in[28];
  const void* n1_b   = d_in[29];
  const void* n2_w   = d_in[30];
  const void* n2_b   = d_in[31];
  const int* eidx    = (const int*)d_in[32];
  const int* srcv = eidx;
  const int* dstv = eidx + NE;

  char* p = (char*)d_ws;
  auto carve = [&](size_t bytes) -> char* {
    char* r = p;
    p += (bytes + 255) & ~(size_t)255;
    return r;
  };
  float* h      = (float*)carve((size_t)NN * 128 * 4);
  float* hp     = (float*)carve((size_t)NN * 128 * 4);
  float* asrc   = (float*)carve((size_t)NN * 4 * 4);
  float* adst   = (float*)carve((size_t)NN * 4 * 4);
  float* ae1    = (float*)carve((size_t)NE * 4 * 4);
  float* ae2    = (float*)carve((size_t)NE * 4 * 4);
  int*   deg    = (int*)carve((size_t)NN * 4);
  int*   indptr = (int*)carve((size_t)(NN + 1) * 4);
  int*   cursor = (int*)carve((size_t)NN * 4);
  int*   csr    = (int*)carve((size_t)NE * 4);
  int*   blks   = (int*)carve(512 * 4);
  float* V      = (float*)carve(128 * 8 * 4);
  float* tbl    = (float*)carve((size_t)TBLN * 8 * 4);
  int*   dflag  = (int*)carve(256);

  hipMemsetAsync(deg, 0, (size_t)NN * 4, stream);
  hipMemsetAsync(cursor, 0, (size_t)NN * 4, stream);

  const int SCB = (NN + 511) / 512;  // 98
  detect_k<<<1, 256, 0, stream>>>((const u16*)x, dflag);
  build_V<<<1, 256, 0, stream>>>(g1_ew, g1_ae, g2_ew, g2_ae, V, dflag);
  build_table<<<TBLN, 128, 0, stream>>>(ta_w1, ta_b1, ta_lnw, ta_lnb, ta_w2,
                                        ta_b2, V, tbl, dflag);
  input_proj<<<NN / 4, 256, 0, stream>>>(x, ip_w1, ip_b1, ip_lnw, ip_lnb,
                                         ip_w2, ip_b2, pn_w, pn_b, h, dflag);
  edge_apply<<<NE / 256, 256, 0, stream>>>(etime, dstv, tbl, (float4*)ae1,
                                           (float4*)ae2, deg, dflag);
  scan1<<<SCB, 512, 0, stream>>>(deg, indptr, blks);
  scan2<<<1, 128, 0, stream>>>(blks, SCB);
  scan3<<<SCB, 512, 0, stream>>>(indptr, blks);
  fill_csr<<<NE / 256, 256, 0, stream>>>(dstv, indptr, cursor, csr);

  hproj_k<<<NN / 2, 256, 0, stream>>>(h, g1_w, g1_as, g1_ad, hp, asrc, adst, dflag);
  agg_k<0><<<NN / 4, 256, 0, stream>>>(indptr, csr, srcv, ae1, asrc, adst, hp,
                                       h, g1_b, n1_w, n1_b, h, nullptr, dflag);
  hproj_k<<<NN / 2, 256, 0, stream>>>(h, g2_w, g2_as, g2_ad, hp, asrc, adst, dflag);
  agg_k<1><<<NN / 4, 256, 0, stream>>>(indptr, csr, srcv, ae2, asrc, adst, hp,
                                       h, g2_b, n2_w, n2_b, nullptr, d_out, dflag);
}

// Round 4
// 569.360 us; speedup vs baseline: 1.8772x; 1.8772x over previous
//
#include <hip/hip_runtime.h>

typedef unsigned short u16;
typedef __attribute__((ext_vector_type(8))) short bf8_t;   // 8 bf16 in 4 VGPRs
typedef __attribute__((ext_vector_type(4))) float f4_t;

constexpr int NN   = 50000;
constexpr int NE   = 800000;
constexpr int TBLN = 8192;

// ---------- helpers ----------
__device__ __forceinline__ float bf(const u16* p, int i) {
  return __uint_as_float(((unsigned)p[i]) << 16);
}
__device__ __forceinline__ u16 f2b(float f) {
  unsigned u = __float_as_uint(f);
  unsigned r = u + 0x7fffu + ((u >> 16) & 1u);  // RNE
  return (u16)(r >> 16);
}
__device__ __forceinline__ short f2bs(float f) {
  unsigned u = __float_as_uint(f);
  unsigned r = u + 0x7fffu + ((u >> 16) & 1u);
  return (short)(r >> 16);
}
__device__ __forceinline__ float wred64(float v) {
#pragma unroll
  for (int o = 32; o; o >>= 1) v += __shfl_xor(v, o);
  return v;
}
__device__ __forceinline__ bf8_t ldv(const u16* p) { return *(const bf8_t*)p; }
__device__ __forceinline__ bf8_t ldcvt(const float* p) {
  const float4 a = *(const float4*)p;
  const float4 b = *(const float4*)(p + 4);
  bf8_t r;
  r[0] = f2bs(a.x); r[1] = f2bs(a.y); r[2] = f2bs(a.z); r[3] = f2bs(a.w);
  r[4] = f2bs(b.x); r[5] = f2bs(b.y); r[6] = f2bs(b.z); r[7] = f2bs(b.w);
  return r;
}
__device__ __forceinline__ f4_t mfma16(bf8_t a, bf8_t b, f4_t c) {
  return __builtin_amdgcn_mfma_f32_16x16x32_bf16(a, b, c, 0, 0, 0);
}

// ---------- weight transpose + fp32->bf16 convert: dst[c*R+r] = bf16(src[r*C+c]) ----------
__global__ void tcvt_k(const float* __restrict__ src, u16* __restrict__ dst,
                       int R, int C) {
  int idx = blockIdx.x * 256 + threadIdx.x;
  if (idx >= R * C) return;
  int r = idx / C, c = idx - r * C;
  dst[c * R + r] = f2b(src[idx]);
}

// ---------- fold edge-attention vectors: V[k][0..3]=layer1, V[k][4..7]=layer2 ----------
__global__ void build_V(const float* __restrict__ ew1, const float* __restrict__ ate1,
                        const float* __restrict__ ew2, const float* __restrict__ ate2,
                        float* __restrict__ V) {
  const int t = threadIdx.x;
#pragma unroll
  for (int rep = 0; rep < 2; ++rep) {
    int idx = t + rep * 256;
    int k = idx >> 2, hd = idx & 3;
    float s1 = 0.f, s2 = 0.f;
    for (int c = 0; c < 32; ++c) {
      s1 += ew1[k * 128 + hd * 32 + c] * ate1[hd * 32 + c];
      s2 += ew2[k * 128 + hd * 32 + c] * ate2[hd * 32 + c];
    }
    V[k * 8 + hd] = s1;
    V[k * 8 + 4 + hd] = s2;
  }
}

// ---------- tabulate a_edge(t): exact temporal MLP at TBLN grid points ----------
__global__ __launch_bounds__(128) void build_table(
    const float* __restrict__ taw1, const float* __restrict__ tab1,
    const float* __restrict__ talnw, const float* __restrict__ talnb,
    const float* __restrict__ taw2, const float* __restrict__ tab2,
    const float* __restrict__ V, float* __restrict__ tbl) {
  const int j = threadIdx.x;
  const int wv = j >> 6, ln = j & 63;
  const float t = (float)blockIdx.x / (float)(TBLN - 1);
  __shared__ float part[4];
  __shared__ float ush[128];
  __shared__ float pacc[16];
  float v = t * taw1[j] + tab1[j];
  float s = wred64(v), sq = wred64(v * v);
  if (ln == 0) { part[wv * 2] = s; part[wv * 2 + 1] = sq; }
  __syncthreads();
  float S = part[0] + part[2], SQ = part[1] + part[3];
  float mu = S * (1.f / 128.f);
  float var = SQ * (1.f / 128.f) - mu * mu;
  float rstd = rsqrtf(var + 1e-5f);
  float u = fmaxf((v - mu) * rstd * talnw[j] + talnb[j], 0.f);
  ush[j] = u;
  __syncthreads();
  float acc = 0.f;
  for (int k = 0; k < 128; ++k) acc += ush[k] * taw2[k * 128 + j];
  float w = tanhf(acc + tab2[j]);
  w = fminf(fmaxf(w, -3.f), 3.f);
#pragma unroll
  for (int p = 0; p < 8; ++p) {
    float z = wred64(w * V[j * 8 + p]);
    if (ln == 0) pacc[wv * 8 + p] = z;
  }
  __syncthreads();
  if (j < 8) tbl[blockIdx.x * 8 + j] = pacc[j] + pacc[8 + j];
}

// ---------- MFMA input projection: 32 rows/block ----------
__global__ __launch_bounds__(256) void ip_mfma(
    const float* __restrict__ x, const u16* __restrict__ w1t,
    const float* __restrict__ b1, const float* __restrict__ ln1w,
    const float* __restrict__ ln1b, const u16* __restrict__ w2t,
    const float* __restrict__ b2, const float* __restrict__ pnw,
    const float* __restrict__ pnb, u16* __restrict__ h16) {
  __shared__ char smem[50176];
  float* h1f = (float*)smem;              // [32][260] fp32
  u16* h1n = (u16*)(smem + 33280);        // [32][264] bf16
  u16* h2n = h1n;                         // alias, reused after GEMM2

  const int t = threadIdx.x;
  const int w = t >> 6, lane = t & 63, q = lane >> 4, l15 = lane & 15;
  const int rowbase = blockIdx.x * 32;

  // GEMM1: [32,128] @ [128,256]
  f4_t acc[2][4];
#pragma unroll
  for (int mt = 0; mt < 2; ++mt)
#pragma unroll
    for (int nt = 0; nt < 4; ++nt) acc[mt][nt] = (f4_t){0.f, 0.f, 0.f, 0.f};
#pragma unroll
  for (int kst = 0; kst < 4; ++kst) {
    int k0 = kst * 32 + q * 8;
    int r0 = rowbase + l15;      if (r0 > NN - 1) r0 = NN - 1;
    int r1 = rowbase + 16 + l15; if (r1 > NN - 1) r1 = NN - 1;
    bf8_t a0 = ldcvt(x + r0 * 128 + k0);
    bf8_t a1 = ldcvt(x + r1 * 128 + k0);
#pragma unroll
    for (int nt = 0; nt < 4; ++nt) {
      int n = w * 64 + nt * 16 + l15;
      bf8_t b = ldv(w1t + n * 128 + k0);
      acc[0][nt] = mfma16(a0, b, acc[0][nt]);
      acc[1][nt] = mfma16(a1, b, acc[1][nt]);
    }
  }
#pragma unroll
  for (int mt = 0; mt < 2; ++mt)
#pragma unroll
    for (int nt = 0; nt < 4; ++nt) {
      int col = w * 64 + nt * 16 + l15;
      float bb = b1[col];
#pragma unroll
      for (int r = 0; r < 4; ++r) {
        int row = mt * 16 + q * 4 + r;
        h1f[row * 260 + col] = fmaxf(acc[mt][nt][r] + bb, 0.f);
      }
    }
  __syncthreads();
  // LN over 256 cols: 8 threads/row, strided cols
  {
    const int row = t >> 3, sub = t & 7;
    const float* rp = h1f + row * 260;
    float sum = 0.f, sq = 0.f;
#pragma unroll
    for (int i = 0; i < 32; ++i) {
      float v = rp[sub + 8 * i];
      sum += v; sq += v * v;
    }
#pragma unroll
    for (int o = 1; o < 8; o <<= 1) { sum += __shfl_xor(sum, o); sq += __shfl_xor(sq, o); }
    float mu = sum * (1.f / 256.f);
    float var = sq * (1.f / 256.f) - mu * mu;
    float rstd = rsqrtf(var + 1e-5f);
#pragma unroll
    for (int i = 0; i < 32; ++i) {
      int c = sub + 8 * i;
      float v = (rp[c] - mu) * rstd * ln1w[c] + ln1b[c];
      h1n[row * 264 + c] = f2b(v);
    }
  }
  __syncthreads();
  // GEMM2: [32,256] @ [256,128]
  f4_t acc2[2][2];
#pragma unroll
  for (int mt = 0; mt < 2; ++mt)
#pragma unroll
    for (int nt = 0; nt < 2; ++nt) acc2[mt][nt] = (f4_t){0.f, 0.f, 0.f, 0.f};
#pragma unroll
  for (int kst = 0; kst < 8; ++kst) {
    int k0 = kst * 32 + q * 8;
    bf8_t a0 = ldv(h1n + (l15) * 264 + k0);
    bf8_t a1 = ldv(h1n + (16 + l15) * 264 + k0);
#pragma unroll
    for (int nt = 0; nt < 2; ++nt) {
      int n = w * 32 + nt * 16 + l15;
      bf8_t b = ldv(w2t + n * 256 + k0);
      acc2[0][nt] = mfma16(a0, b, acc2[0][nt]);
      acc2[1][nt] = mfma16(a1, b, acc2[1][nt]);
    }
  }
  __syncthreads();
#pragma unroll
  for (int mt = 0; mt < 2; ++mt)
#pragma unroll
    for (int nt = 0; nt < 2; ++nt) {
      int col = w * 32 + nt * 16 + l15;
      float bb = b2[col];
#pragma unroll
      for (int r = 0; r < 4; ++r) {
        int row = mt * 16 + q * 4 + r;
        h1f[row * 132 + col] = acc2[mt][nt][r] + bb;
      }
    }
  __syncthreads();
  // LN over 128 + relu + clip -> h2n (bf16)
  {
    const int row = t >> 3, sub = t & 7;
    const float* rp = h1f + row * 132;
    float sum = 0.f, sq = 0.f;
#pragma unroll
    for (int i = 0; i < 16; ++i) {
      float v = rp[sub + 8 * i];
      sum += v; sq += v * v;
    }
#pragma unroll
    for (int o = 1; o < 8; o <<= 1) { sum += __shfl_xor(sum, o); sq += __shfl_xor(sq, o); }
    float mu = sum * (1.f / 128.f);
    float var = sq * (1.f / 128.f) - mu * mu;
    float rstd = rsqrtf(var + 1e-5f);
#pragma unroll
    for (int i = 0; i < 16; ++i) {
      int c = sub + 8 * i;
      float v = (rp[c] - mu) * rstd * pnw[c] + pnb[c];
      v = fminf(fmaxf(v, 0.f), 10.f);
      h2n[row * 128 + c] = f2b(v);
    }
  }
  __syncthreads();
  // coalesced 32B stores
  {
    const int row = t >> 3, cb = (t & 7) * 16;
    int rg = rowbase + row;
    if (rg < NN) {
      uint4 v0 = *(const uint4*)(h2n + row * 128 + cb);
      uint4 v1 = *(const uint4*)(h2n + row * 128 + cb + 8);
      *(uint4*)(h16 + rg * 128 + cb) = v0;
      *(uint4*)(h16 + rg * 128 + cb + 8) = v1;
    }
  }
}

// ---------- MFMA node projection + attention logits; head == wave ----------
__global__ __launch_bounds__(256) void hp_mfma(
    const u16* __restrict__ feat16, const u16* __restrict__ wt,
    const float* __restrict__ attsrc, const float* __restrict__ attdst,
    u16* __restrict__ hp16, float* __restrict__ asrc, float* __restrict__ adst) {
  const int t = threadIdx.x;
  const int w = t >> 6, lane = t & 63, q = lane >> 4, l15 = lane & 15;
  const int rowbase = blockIdx.x * 32;
  f4_t acc[2][2];
#pragma unroll
  for (int mt = 0; mt < 2; ++mt)
#pragma unroll
    for (int nt = 0; nt < 2; ++nt) acc[mt][nt] = (f4_t){0.f, 0.f, 0.f, 0.f};
#pragma unroll
  for (int kst = 0; kst < 4; ++kst) {
    int k0 = kst * 32 + q * 8;
    int r0 = rowbase + l15;      if (r0 > NN - 1) r0 = NN - 1;
    int r1 = rowbase + 16 + l15; if (r1 > NN - 1) r1 = NN - 1;
    bf8_t a0 = ldv(feat16 + r0 * 128 + k0);
    bf8_t a1 = ldv(feat16 + r1 * 128 + k0);
#pragma unroll
    for (int nt = 0; nt < 2; ++nt) {
      int n = w * 32 + nt * 16 + l15;
      bf8_t b = ldv(wt + n * 128 + k0);
      acc[0][nt] = mfma16(a0, b, acc[0][nt]);
      acc[1][nt] = mfma16(a1, b, acc[1][nt]);
    }
  }
  float ps[2][4], pd[2][4];
#pragma unroll
  for (int mt = 0; mt < 2; ++mt)
#pragma unroll
    for (int r = 0; r < 4; ++r) { ps[mt][r] = 0.f; pd[mt][r] = 0.f; }
#pragma unroll
  for (int mt = 0; mt < 2; ++mt)
#pragma unroll
    for (int nt = 0; nt < 2; ++nt) {
      int col = w * 32 + nt * 16 + l15;
      float as = attsrc[col], ad = attdst[col];
#pragma unroll
      for (int r = 0; r < 4; ++r) {
        int row = mt * 16 + q * 4 + r;
        int rg = rowbase + row;
        float v = acc[mt][nt][r];
        if (rg < NN) hp16[(size_t)rg * 128 + col] = f2b(v);
        ps[mt][r] += v * as;
        pd[mt][r] += v * ad;
      }
    }
#pragma unroll
  for (int o = 1; o < 16; o <<= 1)
#pragma unroll
    for (int mt = 0; mt < 2; ++mt)
#pragma unroll
      for (int r = 0; r < 4; ++r) {
        ps[mt][r] += __shfl_xor(ps[mt][r], o);
        pd[mt][r] += __shfl_xor(pd[mt][r], o);
      }
  if (l15 == 0) {
#pragma unroll
    for (int mt = 0; mt < 2; ++mt)
#pragma unroll
      for (int r = 0; r < 4; ++r) {
        int rg = rowbase + mt * 16 + q * 4 + r;
        if (rg < NN) {
          asrc[rg * 4 + w] = ps[mt][r];
          adst[rg * 4 + w] = pd[mt][r];
        }
      }
  }
}

// ---------- deg histogram ----------
__global__ __launch_bounds__(256) void deg_k(const int* __restrict__ dstv,
                                             int* __restrict__ deg) {
  int e = blockIdx.x * 256 + threadIdx.x;
  if (e < NE) atomicAdd(&deg[dstv[e]], 1);
}

// ---------- scans ----------
__global__ __launch_bounds__(512) void scan1(const int* __restrict__ deg,
                                             int* __restrict__ indptr,
                                             int* __restrict__ blks) {
  const int t = threadIdx.x;
  const int i = blockIdx.x * 512 + t;
  int v = (i < NN) ? deg[i] : 0;
  const int lane = t & 63, wv = t >> 6;
  int x = v;
#pragma unroll
  for (int o = 1; o < 64; o <<= 1) {
    int y = __shfl_up(x, o);
    if (lane >= o) x += y;
  }
  __shared__ int ws[8];
  if (lane == 63) ws[wv] = x;
  __syncthreads();
  if (t < 8) {
    int y = ws[t];
#pragma unroll
    for (int o = 1; o < 8; o <<= 1) {
      int z = __shfl_up(y, o);
      if (t >= o) y += z;
    }
    ws[t] = y;
  }
  __syncthreads();
  int excl = wv ? ws[wv - 1] : 0;
  x += excl;
  if (i < NN) indptr[i + 1] = x;
  if (t == 511) blks[blockIdx.x] = x;
}
__global__ void scan2(int* __restrict__ blks, int nb) {
  const int t = threadIdx.x;
  int v = (t < nb) ? blks[t] : 0;
  const int lane = t & 63, wv = t >> 6;
  int x = v;
#pragma unroll
  for (int o = 1; o < 64; o <<= 1) {
    int y = __shfl_up(x, o);
    if (lane >= o) x += y;
  }
  __shared__ int ws[2];
  if (lane == 63) ws[wv] = x;
  __syncthreads();
  if (wv == 1) x += ws[0];
  if (t < nb) blks[t] = x - v;
}
__global__ __launch_bounds__(512) void scan3(int* __restrict__ indptr,
                                             const int* __restrict__ blks) {
  const int i = blockIdx.x * 512 + threadIdx.x;
  if (i < NN) indptr[i + 1] += blks[blockIdx.x];
  if (i == 0) indptr[0] = 0;
}

// ---------- fill CSR-ordered edge arrays + lerped logits ----------
__global__ __launch_bounds__(256) void fill_fused(
    const int* __restrict__ srcv, const int* __restrict__ dstv,
    const float* __restrict__ etime, const float* __restrict__ tbl,
    const int* __restrict__ indptr, int* __restrict__ cursor,
    int* __restrict__ es, float4* __restrict__ aec1, float4* __restrict__ aec2) {
  const int e = blockIdx.x * 256 + threadIdx.x;
  if (e >= NE) return;
  int d = dstv[e];
  int p = atomicAdd(&cursor[d], 1);
  int pos = indptr[d] + p;
  es[pos] = srcv[e];
  float t = etime[e];
  t = fminf(fmaxf(t, 0.f), 1.f);
  float fpos = t * (float)(TBLN - 1);
  int i0 = (int)fpos;
  if (i0 > TBLN - 2) i0 = TBLN - 2;
  float fr = fpos - (float)i0;
  const float4* r = (const float4*)(tbl + i0 * 8);
  float4 a0 = r[0], a1 = r[1], b0 = r[2], b1 = r[3];
  float4 o1, o2;
  o1.x = a0.x + fr * (b0.x - a0.x); o1.y = a0.y + fr * (b0.y - a0.y);
  o1.z = a0.z + fr * (b0.z - a0.z); o1.w = a0.w + fr * (b0.w - a0.w);
  o2.x = a1.x + fr * (b1.x - a1.x); o2.y = a1.y + fr * (b1.y - a1.y);
  o2.z = a1.z + fr * (b1.z - a1.z); o2.w = a1.w + fr * (b1.w - a1.w);
  aec1[pos] = o1;
  aec2[pos] = o2;
}

// ---------- GAT aggregation: one wave per node, shfl-broadcast pass B ----------
template <int FINAL>
__global__ __launch_bounds__(256) void agg_k(
    const int* __restrict__ indptr, const int* __restrict__ es,
    const float4* __restrict__ aec, const float* __restrict__ asrc,
    const float* __restrict__ adst, const u16* __restrict__ hp16,
    const u16* __restrict__ feat16, const float* __restrict__ gbias,
    const float* __restrict__ lnw, const float* __restrict__ lnb,
    u16* __restrict__ gout16, float* __restrict__ out32) {
  const int wv = threadIdx.x >> 6, lane = threadIdx.x & 63;
  const int n = blockIdx.x * 4 + wv;
  if (n >= NN) return;
  const int s0 = indptr[n], s1 = indptr[n + 1];
  const int dg = s1 - s0;
  const float4 adv = *(const float4*)(adst + n * 4);
  const float ad[4] = {adv.x, adv.y, adv.z, adv.w};
  float m[4] = {-INFINITY, -INFINITY, -INFINITY, -INFINITY};
  float ss[4] = {0.f, 0.f, 0.f, 0.f};
  float sa[4] = {0.f, 0.f, 0.f, 0.f};
  int sc_sv = 0;
  float l_sv[4] = {0.f, 0.f, 0.f, 0.f};
  for (int base = s0; base < s1; base += 64) {
    int idx = base + lane;
    if (idx < s1) {
      int sc = es[idx];
      float4 av = aec[idx];
      const float4 as = *(const float4*)(asrc + sc * 4);
      float l[4] = {as.x + ad[0] + av.x, as.y + ad[1] + av.y,
                    as.z + ad[2] + av.z, as.w + ad[3] + av.w};
      float avv[4] = {av.x, av.y, av.z, av.w};
#pragma unroll
      for (int h = 0; h < 4; ++h) {
        float lv = fmaxf(l[h], 0.2f * l[h]);
        float mn = fmaxf(m[h], lv);
        ss[h] = ss[h] * __expf(m[h] - mn) + __expf(lv - mn);
        m[h] = mn;
        sa[h] += avv[h];
        if (base == s0) l_sv[h] = lv;
      }
      if (base == s0) sc_sv = sc;
    }
  }
#pragma unroll
  for (int o = 32; o; o >>= 1) {
#pragma unroll
    for (int h = 0; h < 4; ++h) {
      float mo = __shfl_xor(m[h], o);
      float so = __shfl_xor(ss[h], o);
      float ao = __shfl_xor(sa[h], o);
      float mn = fmaxf(m[h], mo);
      float t1 = ss[h] > 0.f ? ss[h] * __expf(m[h] - mn) : 0.f;
      float t2 = so > 0.f ? so * __expf(mo - mn) : 0.f;
      m[h] = mn;
      ss[h] = t1 + t2;
      sa[h] += ao;
    }
  }
  const float degf = (float)(dg > 0 ? dg : 1);
  const float4 asnv = *(const float4*)(asrc + n * 4);
  const float asn[4] = {asnv.x, asnv.y, asnv.z, asnv.w};
  float rs[4], aself[4];
#pragma unroll
  for (int h = 0; h < 4; ++h) {
    float la = asn[h] + ad[h] + sa[h] / degf;
    la = fmaxf(la, 0.2f * la);
    float mn = fmaxf(m[h], la);
    float t1 = ss[h] > 0.f ? ss[h] * __expf(m[h] - mn) : 0.f;
    ss[h] = t1 + __expf(la - mn);
    m[h] = mn;
    rs[h] = 1.f / (ss[h] + 1e-16f);
    aself[h] = __expf(la - m[h]) * rs[h];
  }
  const int hh = lane >> 5;
  const int ch0 = lane, ch1 = lane + 64;
  float acc0 = (hh ? aself[1] : aself[0]) * bf(hp16, n * 128 + ch0);
  float acc1 = (hh ? aself[3] : aself[2]) * bf(hp16, n * 128 + ch1);
  for (int base = s0; base < s1; base += 64) {
    int cnt = s1 - base; if (cnt > 64) cnt = 64;
    int sc;
    float w0, w1, w2, w3;
    if (base == s0) {
      sc = sc_sv;
      w0 = __expf(l_sv[0] - m[0]) * rs[0];
      w1 = __expf(l_sv[1] - m[1]) * rs[1];
      w2 = __expf(l_sv[2] - m[2]) * rs[2];
      w3 = __expf(l_sv[3] - m[3]) * rs[3];
    } else {
      int idx = base + lane;
      int ii = idx < s1 ? idx : s1 - 1;
      sc = es[ii];
      float4 av = aec[ii];
      const float4 as = *(const float4*)(asrc + sc * 4);
      float l0 = as.x + ad[0] + av.x, l1 = as.y + ad[1] + av.y;
      float l2 = as.z + ad[2] + av.z, l3 = as.w + ad[3] + av.w;
      l0 = fmaxf(l0, 0.2f * l0); l1 = fmaxf(l1, 0.2f * l1);
      l2 = fmaxf(l2, 0.2f * l2); l3 = fmaxf(l3, 0.2f * l3);
      w0 = __expf(l0 - m[0]) * rs[0];
      w1 = __expf(l1 - m[1]) * rs[1];
      w2 = __expf(l2 - m[2]) * rs[2];
      w3 = __expf(l3 - m[3]) * rs[3];
    }
    for (int j = 0; j < cnt; ++j) {
      int bsc = __shfl(sc, j);
      float b0 = __shfl(w0, j), b1 = __shfl(w1, j);
      float b2 = __shfl(w2, j), b3 = __shfl(w3, j);
      float wA = hh ? b1 : b0;
      float wB = hh ? b3 : b2;
      acc0 += wA * bf(hp16, (size_t)bsc * 128 + ch0);
      acc1 += wB * bf(hp16, (size_t)bsc * 128 + ch1);
    }
  }
  float v0 = acc0 + gbias[ch0] + bf(feat16, (size_t)n * 128 + ch0);
  float v1 = acc1 + gbias[ch1] + bf(feat16, (size_t)n * 128 + ch1);
  v0 = fminf(fmaxf(v0, -10.f), 10.f);
  v1 = fminf(fmaxf(v1, -10.f), 10.f);
  float s = wred64(v0 + v1);
  float sq = wred64(v0 * v0 + v1 * v1);
  float mu = s * (1.f / 128.f);
  float var = sq * (1.f / 128.f) - mu * mu;
  float rstd = rsqrtf(var + 1e-5f);
  float y0 = (v0 - mu) * rstd * lnw[ch0] + lnb[ch0];
  float y1 = (v1 - mu) * rstd * lnw[ch1] + lnb[ch1];
  y0 = y0 > 0.f ? y0 : expm1f(y0);
  y1 = y1 > 0.f ? y1 : expm1f(y1);
  if (FINAL) {
    out32[(size_t)n * 128 + ch0] = y0;
    out32[(size_t)n * 128 + ch1] = y1;
  } else {
    gout16[(size_t)n * 128 + ch0] = f2b(y0);
    gout16[(size_t)n * 128 + ch1] = f2b(y1);
  }
}

// ---------- launch ----------
extern "C" void kernel_launch(void* const* d_in, const int* in_sizes, int n_in,
                              void* d_out, int out_size, void* d_ws, size_t ws_size,
                              hipStream_t stream) {
  const float* x      = (const float*)d_in[0];
  const float* etime  = (const float*)d_in[1];
  const float* ip_w1  = (const float*)d_in[2];
  const float* ip_b1  = (const float*)d_in[3];
  const float* ip_lnw = (const float*)d_in[4];
  const float* ip_lnb = (const float*)d_in[5];
  const float* ip_w2  = (const float*)d_in[6];
  const float* ip_b2  = (const float*)d_in[7];
  const float* pn_w   = (const float*)d_in[8];
  const float* pn_b   = (const float*)d_in[9];
  const float* ta_w1  = (const float*)d_in[10];
  const float* ta_b1  = (const float*)d_in[11];
  const float* ta_lnw = (const float*)d_in[12];
  const float* ta_lnb = (const float*)d_in[13];
  const float* ta_w2  = (const float*)d_in[14];
  const float* ta_b2  = (const float*)d_in[15];
  const float* g1_w   = (const float*)d_in[16];
  const float* g1_as  = (const float*)d_in[17];
  const float* g1_ad  = (const float*)d_in[18];
  const float* g1_ew  = (const float*)d_in[19];
  const float* g1_ae  = (const float*)d_in[20];
  const float* g1_b   = (const float*)d_in[21];
  const float* g2_w   = (const float*)d_in[22];
  const float* g2_as  = (const float*)d_in[23];
  const float* g2_ad  = (const float*)d_in[24];
  const float* g2_ew  = (const float*)d_in[25];
  const float* g2_ae  = (const float*)d_in[26];
  const float* g2_b   = (const float*)d_in[27];
  const float* n1_w   = (const float*)d_in[28];
  const float* n1_b   = (const float*)d_in[29];
  const float* n2_w   = (const float*)d_in[30];
  const float* n2_b   = (const float*)d_in[31];
  const int* eidx     = (const int*)d_in[32];
  const int* srcv = eidx;
  const int* dstv = eidx + NE;

  char* p = (char*)d_ws;
  auto carve = [&](size_t bytes) -> char* {
    char* r = p;
    p += (bytes + 255) & ~(size_t)255;
    return r;
  };
  u16*   h16    = (u16*)carve((size_t)NN * 128 * 2);
  u16*   g16    = (u16*)carve((size_t)NN * 128 * 2);
  u16*   hp16   = (u16*)carve((size_t)NN * 128 * 2);
  float* asrc   = (float*)carve((size_t)NN * 4 * 4);
  float* adst   = (float*)carve((size_t)NN * 4 * 4);
  int*   es     = (int*)carve((size_t)NE * 4);
  float4* aec1  = (float4*)carve((size_t)NE * 16);
  float4* aec2  = (float4*)carve((size_t)NE * 16);
  int*   deg    = (int*)carve((size_t)NN * 4);
  int*   indptr = (int*)carve((size_t)(NN + 1) * 4);
  int*   cursor = (int*)carve((size_t)NN * 4);
  int*   blks   = (int*)carve(512 * 4);
  float* V      = (float*)carve(128 * 8 * 4);
  float* tbl    = (float*)carve((size_t)TBLN * 8 * 4);
  u16*   w1t    = (u16*)carve(128 * 256 * 2);
  u16*   w2t    = (u16*)carve(256 * 128 * 2);
  u16*   g1wt   = (u16*)carve(128 * 128 * 2);
  u16*   g2wt   = (u16*)carve(128 * 128 * 2);

  hipMemsetAsync(deg, 0, (size_t)NN * 4, stream);
  hipMemsetAsync(cursor, 0, (size_t)NN * 4, stream);

  const int SCB = (NN + 511) / 512;
  const int MB = (NN + 31) / 32;  // 1563

  build_V<<<1, 256, 0, stream>>>(g1_ew, g1_ae, g2_ew, g2_ae, V);
  build_table<<<TBLN, 128, 0, stream>>>(ta_w1, ta_b1, ta_lnw, ta_lnb, ta_w2, ta_b2, V, tbl);
  tcvt_k<<<128, 256, 0, stream>>>(ip_w1, w1t, 128, 256);
  tcvt_k<<<128, 256, 0, stream>>>(ip_w2, w2t, 256, 128);
  tcvt_k<<<64, 256, 0, stream>>>(g1_w, g1wt, 128, 128);
  tcvt_k<<<64, 256, 0, stream>>>(g2_w, g2wt, 128, 128);
  deg_k<<<NE / 256, 256, 0, stream>>>(dstv, deg);
  scan1<<<SCB, 512, 0, stream>>>(deg, indptr, blks);
  scan2<<<1, 128, 0, stream>>>(blks, SCB);
  scan3<<<SCB, 512, 0, stream>>>(indptr, blks);
  fill_fused<<<NE / 256, 256, 0, stream>>>(srcv, dstv, etime, tbl, indptr, cursor,
                                           es, aec1, aec2);
  ip_mfma<<<MB, 256, 0, stream>>>(x, w1t, ip_b1, ip_lnw, ip_lnb, w2t, ip_b2,
                                  pn_w, pn_b, h16);
  hp_mfma<<<MB, 256, 0, stream>>>(h16, g1wt, g1_as, g1_ad, hp16, asrc, adst);
  agg_k<0><<<NN / 4, 256, 0, stream>>>(indptr, es, aec1, asrc, adst, hp16, h16,
                                       g1_b, n1_w, n1_b, g16, nullptr);
  hp_mfma<<<MB, 256, 0, stream>>>(g16, g2wt, g2_as, g2_ad, hp16, asrc, adst);
  agg_k<1><<<NN / 4, 256, 0, stream>>>(indptr, es, aec2, asrc, adst, hp16, g16,
                                       g2_b, n2_w, n2_b, nullptr, (float*)d_out);
}

// Round 5
// 451.724 us; speedup vs baseline: 2.3661x; 1.2604x over previous
//
#include <hip/hip_runtime.h>

typedef unsigned short u16;
typedef __attribute__((ext_vector_type(8))) short bf8_t;   // 8 bf16 in 4 VGPRs
typedef __attribute__((ext_vector_type(4))) float f4_t;

constexpr int NN   = 50000;
constexpr int NE   = 800000;
constexpr int TBLN = 2048;

// ---------- helpers ----------
__device__ __forceinline__ float bf(const u16* p, int i) {
  return __uint_as_float(((unsigned)p[i]) << 16);
}
__device__ __forceinline__ u16 f2b(float f) {
  unsigned u = __float_as_uint(f);
  unsigned r = u + 0x7fffu + ((u >> 16) & 1u);  // RNE
  return (u16)(r >> 16);
}
__device__ __forceinline__ short f2bs(float f) {
  unsigned u = __float_as_uint(f);
  unsigned r = u + 0x7fffu + ((u >> 16) & 1u);
  return (short)(r >> 16);
}
__device__ __forceinline__ float blo(unsigned u) { return __uint_as_float(u << 16); }
__device__ __forceinline__ float bhi(unsigned u) { return __uint_as_float(u & 0xffff0000u); }
__device__ __forceinline__ float wred64(float v) {
#pragma unroll
  for (int o = 32; o; o >>= 1) v += __shfl_xor(v, o);
  return v;
}
__device__ __forceinline__ bf8_t ldv(const u16* p) { return *(const bf8_t*)p; }
__device__ __forceinline__ bf8_t ldcvt(const float* p) {
  const float4 a = *(const float4*)p;
  const float4 b = *(const float4*)(p + 4);
  bf8_t r;
  r[0] = f2bs(a.x); r[1] = f2bs(a.y); r[2] = f2bs(a.z); r[3] = f2bs(a.w);
  r[4] = f2bs(b.x); r[5] = f2bs(b.y); r[6] = f2bs(b.z); r[7] = f2bs(b.w);
  return r;
}
__device__ __forceinline__ f4_t mfma16(bf8_t a, bf8_t b, f4_t c) {
  return __builtin_amdgcn_mfma_f32_16x16x32_bf16(a, b, c, 0, 0, 0);
}

// ---------- weight transpose + fp32->bf16 convert ----------
__global__ void tcvt_k(const float* __restrict__ src, u16* __restrict__ dst,
                       int R, int C) {
  int idx = blockIdx.x * 256 + threadIdx.x;
  if (idx >= R * C) return;
  int r = idx / C, c = idx - r * C;
  dst[c * R + r] = f2b(src[idx]);
}

// ---------- fold edge-attention vectors ----------
__global__ void build_V(const float* __restrict__ ew1, const float* __restrict__ ate1,
                        const float* __restrict__ ew2, const float* __restrict__ ate2,
                        float* __restrict__ V) {
  const int t = threadIdx.x;
#pragma unroll
  for (int rep = 0; rep < 2; ++rep) {
    int idx = t + rep * 256;
    int k = idx >> 2, hd = idx & 3;
    float s1 = 0.f, s2 = 0.f;
    for (int c = 0; c < 32; ++c) {
      s1 += ew1[k * 128 + hd * 32 + c] * ate1[hd * 32 + c];
      s2 += ew2[k * 128 + hd * 32 + c] * ate2[hd * 32 + c];
    }
    V[k * 8 + hd] = s1;
    V[k * 8 + 4 + hd] = s2;
  }
}

// ---------- tabulate a_edge(t) ----------
__global__ __launch_bounds__(128) void build_table(
    const float* __restrict__ taw1, const float* __restrict__ tab1,
    const float* __restrict__ talnw, const float* __restrict__ talnb,
    const float* __restrict__ taw2, const float* __restrict__ tab2,
    const float* __restrict__ V, float* __restrict__ tbl) {
  const int j = threadIdx.x;
  const int wv = j >> 6, ln = j & 63;
  const float t = (float)blockIdx.x / (float)(TBLN - 1);
  __shared__ float part[4];
  __shared__ float ush[128];
  __shared__ float pacc[16];
  float v = t * taw1[j] + tab1[j];
  float s = wred64(v), sq = wred64(v * v);
  if (ln == 0) { part[wv * 2] = s; part[wv * 2 + 1] = sq; }
  __syncthreads();
  float S = part[0] + part[2], SQ = part[1] + part[3];
  float mu = S * (1.f / 128.f);
  float var = SQ * (1.f / 128.f) - mu * mu;
  float rstd = rsqrtf(var + 1e-5f);
  float u = fmaxf((v - mu) * rstd * talnw[j] + talnb[j], 0.f);
  ush[j] = u;
  __syncthreads();
  float acc = 0.f;
  for (int k = 0; k < 128; ++k) acc += ush[k] * taw2[k * 128 + j];
  float w = tanhf(acc + tab2[j]);
  w = fminf(fmaxf(w, -3.f), 3.f);
#pragma unroll
  for (int p = 0; p < 8; ++p) {
    float z = wred64(w * V[j * 8 + p]);
    if (ln == 0) pacc[wv * 8 + p] = z;
  }
  __syncthreads();
  if (j < 8) tbl[blockIdx.x * 8 + j] = pacc[j] + pacc[8 + j];
}

// ---------- MFMA input projection: 32 rows/block ----------
__global__ __launch_bounds__(256) void ip_mfma(
    const float* __restrict__ x, const u16* __restrict__ w1t,
    const float* __restrict__ b1, const float* __restrict__ ln1w,
    const float* __restrict__ ln1b, const u16* __restrict__ w2t,
    const float* __restrict__ b2, const float* __restrict__ pnw,
    const float* __restrict__ pnb, u16* __restrict__ h16) {
  __shared__ char smem[50176];
  float* h1f = (float*)smem;              // [32][260] fp32
  u16* h1n = (u16*)(smem + 33280);        // [32][264] bf16
  u16* h2n = h1n;                         // alias, reused after GEMM2

  const int t = threadIdx.x;
  const int w = t >> 6, lane = t & 63, q = lane >> 4, l15 = lane & 15;
  const int rowbase = blockIdx.x * 32;

  // GEMM1: [32,128] @ [128,256]
  f4_t acc[2][4];
#pragma unroll
  for (int mt = 0; mt < 2; ++mt)
#pragma unroll
    for (int nt = 0; nt < 4; ++nt) acc[mt][nt] = (f4_t){0.f, 0.f, 0.f, 0.f};
#pragma unroll
  for (int kst = 0; kst < 4; ++kst) {
    int k0 = kst * 32 + q * 8;
    int r0 = rowbase + l15;      if (r0 > NN - 1) r0 = NN - 1;
    int r1 = rowbase + 16 + l15; if (r1 > NN - 1) r1 = NN - 1;
    bf8_t a0 = ldcvt(x + r0 * 128 + k0);
    bf8_t a1 = ldcvt(x + r1 * 128 + k0);
#pragma unroll
    for (int nt = 0; nt < 4; ++nt) {
      int n = w * 64 + nt * 16 + l15;
      bf8_t b = ldv(w1t + n * 128 + k0);
      acc[0][nt] = mfma16(a0, b, acc[0][nt]);
      acc[1][nt] = mfma16(a1, b, acc[1][nt]);
    }
  }
#pragma unroll
  for (int mt = 0; mt < 2; ++mt)
#pragma unroll
    for (int nt = 0; nt < 4; ++nt) {
      int col = w * 64 + nt * 16 + l15;
      float bb = b1[col];
#pragma unroll
      for (int r = 0; r < 4; ++r) {
        int row = mt * 16 + q * 4 + r;
        h1f[row * 260 + col] = fmaxf(acc[mt][nt][r] + bb, 0.f);
      }
    }
  __syncthreads();
  // LN over 256 cols
  {
    const int row = t >> 3, sub = t & 7;
    const float* rp = h1f + row * 260;
    float sum = 0.f, sq = 0.f;
#pragma unroll
    for (int i = 0; i < 32; ++i) {
      float v = rp[sub + 8 * i];
      sum += v; sq += v * v;
    }
#pragma unroll
    for (int o = 1; o < 8; o <<= 1) { sum += __shfl_xor(sum, o); sq += __shfl_xor(sq, o); }
    float mu = sum * (1.f / 256.f);
    float var = sq * (1.f / 256.f) - mu * mu;
    float rstd = rsqrtf(var + 1e-5f);
#pragma unroll
    for (int i = 0; i < 32; ++i) {
      int c = sub + 8 * i;
      float v = (rp[c] - mu) * rstd * ln1w[c] + ln1b[c];
      h1n[row * 264 + c] = f2b(v);
    }
  }
  __syncthreads();
  // GEMM2: [32,256] @ [256,128]
  f4_t acc2[2][2];
#pragma unroll
  for (int mt = 0; mt < 2; ++mt)
#pragma unroll
    for (int nt = 0; nt < 2; ++nt) acc2[mt][nt] = (f4_t){0.f, 0.f, 0.f, 0.f};
#pragma unroll
  for (int kst = 0; kst < 8; ++kst) {
    int k0 = kst * 32 + q * 8;
    bf8_t a0 = ldv(h1n + (l15) * 264 + k0);
    bf8_t a1 = ldv(h1n + (16 + l15) * 264 + k0);
#pragma unroll
    for (int nt = 0; nt < 2; ++nt) {
      int n = w * 32 + nt * 16 + l15;
      bf8_t b = ldv(w2t + n * 256 + k0);
      acc2[0][nt] = mfma16(a0, b, acc2[0][nt]);
      acc2[1][nt] = mfma16(a1, b, acc2[1][nt]);
    }
  }
  __syncthreads();
#pragma unroll
  for (int mt = 0; mt < 2; ++mt)
#pragma unroll
    for (int nt = 0; nt < 2; ++nt) {
      int col = w * 32 + nt * 16 + l15;
      float bb = b2[col];
#pragma unroll
      for (int r = 0; r < 4; ++r) {
        int row = mt * 16 + q * 4 + r;
        h1f[row * 132 + col] = acc2[mt][nt][r] + bb;
      }
    }
  __syncthreads();
  // LN over 128 + relu + clip -> h2n (bf16)
  {
    const int row = t >> 3, sub = t & 7;
    const float* rp = h1f + row * 132;
    float sum = 0.f, sq = 0.f;
#pragma unroll
    for (int i = 0; i < 16; ++i) {
      float v = rp[sub + 8 * i];
      sum += v; sq += v * v;
    }
#pragma unroll
    for (int o = 1; o < 8; o <<= 1) { sum += __shfl_xor(sum, o); sq += __shfl_xor(sq, o); }
    float mu = sum * (1.f / 128.f);
    float var = sq * (1.f / 128.f) - mu * mu;
    float rstd = rsqrtf(var + 1e-5f);
#pragma unroll
    for (int i = 0; i < 16; ++i) {
      int c = sub + 8 * i;
      float v = (rp[c] - mu) * rstd * pnw[c] + pnb[c];
      v = fminf(fmaxf(v, 0.f), 10.f);
      h2n[row * 128 + c] = f2b(v);
    }
  }
  __syncthreads();
  {
    const int row = t >> 3, cb = (t & 7) * 16;
    int rg = rowbase + row;
    if (rg < NN) {
      uint4 v0 = *(const uint4*)(h2n + row * 128 + cb);
      uint4 v1 = *(const uint4*)(h2n + row * 128 + cb + 8);
      *(uint4*)(h16 + rg * 128 + cb) = v0;
      *(uint4*)(h16 + rg * 128 + cb + 8) = v1;
    }
  }
}

// ---------- MFMA node projection + attention logits ----------
__global__ __launch_bounds__(256) void hp_mfma(
    const u16* __restrict__ feat16, const u16* __restrict__ wt,
    const float* __restrict__ attsrc, const float* __restrict__ attdst,
    u16* __restrict__ hp16, float* __restrict__ asrc, float* __restrict__ adst) {
  const int t = threadIdx.x;
  const int w = t >> 6, lane = t & 63, q = lane >> 4, l15 = lane & 15;
  const int rowbase = blockIdx.x * 32;
  f4_t acc[2][2];
#pragma unroll
  for (int mt = 0; mt < 2; ++mt)
#pragma unroll
    for (int nt = 0; nt < 2; ++nt) acc[mt][nt] = (f4_t){0.f, 0.f, 0.f, 0.f};
#pragma unroll
  for (int kst = 0; kst < 4; ++kst) {
    int k0 = kst * 32 + q * 8;
    int r0 = rowbase + l15;      if (r0 > NN - 1) r0 = NN - 1;
    int r1 = rowbase + 16 + l15; if (r1 > NN - 1) r1 = NN - 1;
    bf8_t a0 = ldv(feat16 + r0 * 128 + k0);
    bf8_t a1 = ldv(feat16 + r1 * 128 + k0);
#pragma unroll
    for (int nt = 0; nt < 2; ++nt) {
      int n = w * 32 + nt * 16 + l15;
      bf8_t b = ldv(wt + n * 128 + k0);
      acc[0][nt] = mfma16(a0, b, acc[0][nt]);
      acc[1][nt] = mfma16(a1, b, acc[1][nt]);
    }
  }
  float ps[2][4], pd[2][4];
#pragma unroll
  for (int mt = 0; mt < 2; ++mt)
#pragma unroll
    for (int r = 0; r < 4; ++r) { ps[mt][r] = 0.f; pd[mt][r] = 0.f; }
#pragma unroll
  for (int mt = 0; mt < 2; ++mt)
#pragma unroll
    for (int nt = 0; nt < 2; ++nt) {
      int col = w * 32 + nt * 16 + l15;
      float as = attsrc[col], ad = attdst[col];
#pragma unroll
      for (int r = 0; r < 4; ++r) {
        int row = mt * 16 + q * 4 + r;
        int rg = rowbase + row;
        float v = acc[mt][nt][r];
        if (rg < NN) hp16[(size_t)rg * 128 + col] = f2b(v);
        ps[mt][r] += v * as;
        pd[mt][r] += v * ad;
      }
    }
#pragma unroll
  for (int o = 1; o < 16; o <<= 1)
#pragma unroll
    for (int mt = 0; mt < 2; ++mt)
#pragma unroll
      for (int r = 0; r < 4; ++r) {
        ps[mt][r] += __shfl_xor(ps[mt][r], o);
        pd[mt][r] += __shfl_xor(pd[mt][r], o);
      }
  if (l15 == 0) {
#pragma unroll
    for (int mt = 0; mt < 2; ++mt)
#pragma unroll
      for (int r = 0; r < 4; ++r) {
        int rg = rowbase + mt * 16 + q * 4 + r;
        if (rg < NN) {
          asrc[rg * 4 + w] = ps[mt][r];
          adst[rg * 4 + w] = pd[mt][r];
        }
      }
  }
}

// ---------- deg histogram ----------
__global__ __launch_bounds__(256) void deg_k(const int* __restrict__ dstv,
                                             int* __restrict__ deg) {
  int e = blockIdx.x * 256 + threadIdx.x;
  if (e < NE) atomicAdd(&deg[dstv[e]], 1);
}

// ---------- scans ----------
__global__ __launch_bounds__(512) void scan1(const int* __restrict__ deg,
                                             int* __restrict__ indptr,
                                             int* __restrict__ blks) {
  const int t = threadIdx.x;
  const int i = blockIdx.x * 512 + t;
  int v = (i < NN) ? deg[i] : 0;
  const int lane = t & 63, wv = t >> 6;
  int x = v;
#pragma unroll
  for (int o = 1; o < 64; o <<= 1) {
    int y = __shfl_up(x, o);
    if (lane >= o) x += y;
  }
  __shared__ int ws[8];
  if (lane == 63) ws[wv] = x;
  __syncthreads();
  if (t < 8) {
    int y = ws[t];
#pragma unroll
    for (int o = 1; o < 8; o <<= 1) {
      int z = __shfl_up(y, o);
      if (t >= o) y += z;
    }
    ws[t] = y;
  }
  __syncthreads();
  int excl = wv ? ws[wv - 1] : 0;
  x += excl;
  if (i < NN) indptr[i + 1] = x;
  if (t == 511) blks[blockIdx.x] = x;
}
__global__ void scan2(int* __restrict__ blks, int nb) {
  const int t = threadIdx.x;
  int v = (t < nb) ? blks[t] : 0;
  const int lane = t & 63, wv = t >> 6;
  int x = v;
#pragma unroll
  for (int o = 1; o < 64; o <<= 1) {
    int y = __shfl_up(x, o);
    if (lane >= o) x += y;
  }
  __shared__ int ws[2];
  if (lane == 63) ws[wv] = x;
  __syncthreads();
  if (wv == 1) x += ws[0];
  if (t < nb) blks[t] = x - v;
}
__global__ __launch_bounds__(512) void scan3(int* __restrict__ indptr,
                                             const int* __restrict__ blks) {
  const int i = blockIdx.x * 512 + threadIdx.x;
  if (i < NN) indptr[i + 1] += blks[blockIdx.x];
  if (i == 0) indptr[0] = 0;
}

// ---------- fill CSR-ordered edge arrays + lerped logits ----------
__global__ __launch_bounds__(256) void fill_fused(
    const int* __restrict__ srcv, const int* __restrict__ dstv,
    const float* __restrict__ etime, const float* __restrict__ tbl,
    const int* __restrict__ indptr, int* __restrict__ cursor,
    int* __restrict__ es, float4* __restrict__ aec1, float4* __restrict__ aec2) {
  const int e = blockIdx.x * 256 + threadIdx.x;
  if (e >= NE) return;
  int d = dstv[e];
  int p = atomicAdd(&cursor[d], 1);
  int pos = indptr[d] + p;
  es[pos] = srcv[e];
  float t = etime[e];
  t = fminf(fmaxf(t, 0.f), 1.f);
  float fpos = t * (float)(TBLN - 1);
  int i0 = (int)fpos;
  if (i0 > TBLN - 2) i0 = TBLN - 2;
  float fr = fpos - (float)i0;
  const float4* r = (const float4*)(tbl + i0 * 8);
  float4 a0 = r[0], a1 = r[1], b0 = r[2], b1 = r[3];
  float4 o1, o2;
  o1.x = a0.x + fr * (b0.x - a0.x); o1.y = a0.y + fr * (b0.y - a0.y);
  o1.z = a0.z + fr * (b0.z - a0.z); o1.w = a0.w + fr * (b0.w - a0.w);
  o2.x = a1.x + fr * (b1.x - a1.x); o2.y = a1.y + fr * (b1.y - a1.y);
  o2.z = a1.z + fr * (b1.z - a1.z); o2.w = a1.w + fr * (b1.w - a1.w);
  aec1[pos] = o1;
  aec2[pos] = o2;
}

// ---------- GAT aggregation: one wave/node; no-max softmax; quad pass B ----------
template <int FINAL>
__global__ __launch_bounds__(256) void agg_k(
    const int* __restrict__ indptr, const int* __restrict__ es,
    const float4* __restrict__ aec, const float* __restrict__ asrc,
    const float* __restrict__ adst, const u16* __restrict__ hp16,
    const u16* __restrict__ feat16, const float* __restrict__ gbias,
    const float* __restrict__ lnw, const float* __restrict__ lnb,
    u16* __restrict__ gout16, float* __restrict__ out32) {
  const int wv = threadIdx.x >> 6, lane = threadIdx.x & 63;
  const int n = blockIdx.x * 4 + wv;
  if (n >= NN) return;
  const int s0 = indptr[n], s1 = indptr[n + 1];
  const int dg = s1 - s0;
  const float4 adv = *(const float4*)(adst + n * 4);
  const float* aef = (const float*)aec;

  // ---- pass A: lane = (edge-offset eo 0..15, head hd2 0..3) ----
  const int eo = lane & 15, hd2 = lane >> 4;
  const float advh2 = hd2 == 0 ? adv.x : hd2 == 1 ? adv.y : hd2 == 2 ? adv.z : adv.w;
  float ssp = 0.f, sap = 0.f;
  for (int base = s0; base < s1; base += 16) {
    int idx = base + eo;
    int ii = idx < s1 ? idx : s1 - 1;
    int sc = es[ii];
    float ae = aef[ii * 4 + hd2];
    float as = asrc[sc * 4 + hd2];
    float l = as + advh2 + ae;
    l = fmaxf(l, 0.2f * l);
    float w = __expf(l);
    if (idx < s1) { ssp += w; sap += ae; }
  }
#pragma unroll
  for (int o = 1; o < 16; o <<= 1) {
    ssp += __shfl_xor(ssp, o);
    sap += __shfl_xor(sap, o);
  }
  // ---- self-loop (per lane, own head hd2) ----
  const float degf = (float)(dg > 0 ? dg : 1);
  float asnh = asrc[n * 4 + hd2];
  float la = asnh + advh2 + sap / degf;
  la = fmaxf(la, 0.2f * la);
  float wsf = __expf(la);
  float inv = 1.f / (ssp + wsf + 1e-16f);
  float wself = wsf * inv;

  // ---- redistribute to pass-B layout: lane needs head hdB = (lane&15)>>2 ----
  const int g = lane >> 4, sl = lane & 15, cb = sl * 8, hdB = sl >> 2;
  const int srcl = hdB * 16;
  const float invB = __shfl(inv, srcl);
  const float wselfB = __shfl(wself, srcl);
  const float advB = __shfl(advh2, srcl);

  // ---- pass B: 16-lane group per edge, 8 ch/lane, unroll x2 ----
  float acc[8];
#pragma unroll
  for (int i = 0; i < 8; ++i) acc[i] = 0.f;
  for (int base = s0; base < s1; base += 8) {
    int i0 = base + g, i1 = base + 4 + g;
    int j0 = i0 < s1 ? i0 : s1 - 1;
    int j1 = i1 < s1 ? i1 : s1 - 1;
    int sc0 = es[j0], sc1 = es[j1];
    float ae0 = aef[j0 * 4 + hdB], ae1 = aef[j1 * 4 + hdB];
    float as0 = asrc[sc0 * 4 + hdB], as1 = asrc[sc1 * 4 + hdB];
    const uint4 r0 = *(const uint4*)(hp16 + (size_t)sc0 * 128 + cb);
    const uint4 r1 = *(const uint4*)(hp16 + (size_t)sc1 * 128 + cb);
    float l0 = as0 + advB + ae0; l0 = fmaxf(l0, 0.2f * l0);
    float l1 = as1 + advB + ae1; l1 = fmaxf(l1, 0.2f * l1);
    float w0 = (i0 < s1) ? __expf(l0) * invB : 0.f;
    float w1 = (i1 < s1) ? __expf(l1) * invB : 0.f;
    acc[0] += w0 * blo(r0.x) + w1 * blo(r1.x);
    acc[1] += w0 * bhi(r0.x) + w1 * bhi(r1.x);
    acc[2] += w0 * blo(r0.y) + w1 * blo(r1.y);
    acc[3] += w0 * bhi(r0.y) + w1 * bhi(r1.y);
    acc[4] += w0 * blo(r0.z) + w1 * blo(r1.z);
    acc[5] += w0 * bhi(r0.z) + w1 * bhi(r1.z);
    acc[6] += w0 * blo(r0.w) + w1 * blo(r1.w);
    acc[7] += w0 * bhi(r0.w) + w1 * bhi(r1.w);
  }
  // reduce across the 4 edge-groups
#pragma unroll
  for (int i = 0; i < 8; ++i) {
    acc[i] += __shfl_xor(acc[i], 16);
    acc[i] += __shfl_xor(acc[i], 32);
  }
  // self contribution + epilogue
  const uint4 rs4 = *(const uint4*)(hp16 + (size_t)n * 128 + cb);
  const uint4 rr4 = *(const uint4*)(feat16 + (size_t)n * 128 + cb);
  const float4 gb0 = *(const float4*)(gbias + cb);
  const float4 gb1 = *(const float4*)(gbias + cb + 4);
  float v[8];
  v[0] = acc[0] + wselfB * blo(rs4.x) + gb0.x + blo(rr4.x);
  v[1] = acc[1] + wselfB * bhi(rs4.x) + gb0.y + bhi(rr4.x);
  v[2] = acc[2] + wselfB * blo(rs4.y) + gb0.z + blo(rr4.y);
  v[3] = acc[3] + wselfB * bhi(rs4.y) + gb0.w + bhi(rr4.y);
  v[4] = acc[4] + wselfB * blo(rs4.z) + gb1.x + blo(rr4.z);
  v[5] = acc[5] + wselfB * bhi(rs4.z) + gb1.y + bhi(rr4.z);
  v[6] = acc[6] + wselfB * blo(rs4.w) + gb1.z + blo(rr4.w);
  v[7] = acc[7] + wselfB * bhi(rs4.w) + gb1.w + bhi(rr4.w);
  float sum = 0.f, sq = 0.f;
#pragma unroll
  for (int i = 0; i < 8; ++i) {
    v[i] = fminf(fmaxf(v[i], -10.f), 10.f);
    sum += v[i]; sq += v[i] * v[i];
  }
#pragma unroll
  for (int o = 1; o < 16; o <<= 1) {
    sum += __shfl_xor(sum, o);
    sq += __shfl_xor(sq, o);
  }
  float mu = sum * (1.f / 128.f);
  float var = sq * (1.f / 128.f) - mu * mu;
  float rstd = rsqrtf(var + 1e-5f);
  const float4 lw0 = *(const float4*)(lnw + cb);
  const float4 lw1 = *(const float4*)(lnw + cb + 4);
  const float4 lb0 = *(const float4*)(lnb + cb);
  const float4 lb1 = *(const float4*)(lnb + cb + 4);
  float y[8];
  y[0] = (v[0] - mu) * rstd * lw0.x + lb0.x;
  y[1] = (v[1] - mu) * rstd * lw0.y + lb0.y;
  y[2] = (v[2] - mu) * rstd * lw0.z + lb0.z;
  y[3] = (v[3] - mu) * rstd * lw0.w + lb0.w;
  y[4] = (v[4] - mu) * rstd * lw1.x + lb1.x;
  y[5] = (v[5] - mu) * rstd * lw1.y + lb1.y;
  y[6] = (v[6] - mu) * rstd * lw1.z + lb1.z;
  y[7] = (v[7] - mu) * rstd * lw1.w + lb1.w;
#pragma unroll
  for (int i = 0; i < 8; ++i) y[i] = y[i] > 0.f ? y[i] : expm1f(y[i]);
  if (g == 0) {
    if (FINAL) {
      float4 o0 = {y[0], y[1], y[2], y[3]};
      float4 o1 = {y[4], y[5], y[6], y[7]};
      *(float4*)(out32 + (size_t)n * 128 + cb) = o0;
      *(float4*)(out32 + (size_t)n * 128 + cb + 4) = o1;
    } else {
      uint4 o;
      o.x = (unsigned)f2b(y[0]) | ((unsigned)f2b(y[1]) << 16);
      o.y = (unsigned)f2b(y[2]) | ((unsigned)f2b(y[3]) << 16);
      o.z = (unsigned)f2b(y[4]) | ((unsigned)f2b(y[5]) << 16);
      o.w = (unsigned)f2b(y[6]) | ((unsigned)f2b(y[7]) << 16);
      *(uint4*)(gout16 + (size_t)n * 128 + cb) = o;
    }
  }
}

// ---------- launch ----------
extern "C" void kernel_launch(void* const* d_in, const int* in_sizes, int n_in,
                              void* d_out, int out_size, void* d_ws, size_t ws_size,
                              hipStream_t stream) {
  const float* x      = (const float*)d_in[0];
  const float* etime  = (const float*)d_in[1];
  const float* ip_w1  = (const float*)d_in[2];
  const float* ip_b1  = (const float*)d_in[3];
  const float* ip_lnw = (const float*)d_in[4];
  const float* ip_lnb = (const float*)d_in[5];
  const float* ip_w2  = (const float*)d_in[6];
  const float* ip_b2  = (const float*)d_in[7];
  const float* pn_w   = (const float*)d_in[8];
  const float* pn_b   = (const float*)d_in[9];
  const float* ta_w1  = (const float*)d_in[10];
  const float* ta_b1  = (const float*)d_in[11];
  const float* ta_lnw = (const float*)d_in[12];
  const float* ta_lnb = (const float*)d_in[13];
  const float* ta_w2  = (const float*)d_in[14];
  const float* ta_b2  = (const float*)d_in[15];
  const float* g1_w   = (const float*)d_in[16];
  const float* g1_as  = (const float*)d_in[17];
  const float* g1_ad  = (const float*)d_in[18];
  const float* g1_ew  = (const float*)d_in[19];
  const float* g1_ae  = (const float*)d_in[20];
  const float* g1_b   = (const float*)d_in[21];
  const float* g2_w   = (const float*)d_in[22];
  const float* g2_as  = (const float*)d_in[23];
  const float* g2_ad  = (const float*)d_in[24];
  const float* g2_ew  = (const float*)d_in[25];
  const float* g2_ae  = (const float*)d_in[26];
  const float* g2_b   = (const float*)d_in[27];
  const float* n1_w   = (const float*)d_in[28];
  const float* n1_b   = (const float*)d_in[29];
  const float* n2_w   = (const float*)d_in[30];
  const float* n2_b   = (const float*)d_in[31];
  const int* eidx     = (const int*)d_in[32];
  const int* srcv = eidx;
  const int* dstv = eidx + NE;

  char* p = (char*)d_ws;
  auto carve = [&](size_t bytes) -> char* {
    char* r = p;
    p += (bytes + 255) & ~(size_t)255;
    return r;
  };
  u16*   h16    = (u16*)carve((size_t)NN * 128 * 2);
  u16*   g16    = (u16*)carve((size_t)NN * 128 * 2);
  u16*   hp16   = (u16*)carve((size_t)NN * 128 * 2);
  float* asrc   = (float*)carve((size_t)NN * 4 * 4);
  float* adst   = (float*)carve((size_t)NN * 4 * 4);
  int*   es     = (int*)carve((size_t)NE * 4);
  float4* aec1  = (float4*)carve((size_t)NE * 16);
  float4* aec2  = (float4*)carve((size_t)NE * 16);
  int*   deg    = (int*)carve((size_t)NN * 4);
  int*   indptr = (int*)carve((size_t)(NN + 1) * 4);
  int*   cursor = (int*)carve((size_t)NN * 4);
  int*   blks   = (int*)carve(512 * 4);
  float* V      = (float*)carve(128 * 8 * 4);
  float* tbl    = (float*)carve((size_t)TBLN * 8 * 4);
  u16*   w1t    = (u16*)carve(128 * 256 * 2);
  u16*   w2t    = (u16*)carve(256 * 128 * 2);
  u16*   g1wt   = (u16*)carve(128 * 128 * 2);
  u16*   g2wt   = (u16*)carve(128 * 128 * 2);

  hipMemsetAsync(deg, 0, (size_t)NN * 4, stream);
  hipMemsetAsync(cursor, 0, (size_t)NN * 4, stream);

  const int SCB = (NN + 511) / 512;
  const int MB = (NN + 31) / 32;  // 1563

  build_V<<<1, 256, 0, stream>>>(g1_ew, g1_ae, g2_ew, g2_ae, V);
  build_table<<<TBLN, 128, 0, stream>>>(ta_w1, ta_b1, ta_lnw, ta_lnb, ta_w2, ta_b2, V, tbl);
  tcvt_k<<<128, 256, 0, stream>>>(ip_w1, w1t, 128, 256);
  tcvt_k<<<128, 256, 0, stream>>>(ip_w2, w2t, 256, 128);
  tcvt_k<<<64, 256, 0, stream>>>(g1_w, g1wt, 128, 128);
  tcvt_k<<<64, 256, 0, stream>>>(g2_w, g2wt, 128, 128);
  deg_k<<<NE / 256, 256, 0, stream>>>(dstv, deg);
  scan1<<<SCB, 512, 0, stream>>>(deg, indptr, blks);
  scan2<<<1, 128, 0, stream>>>(blks, SCB);
  scan3<<<SCB, 512, 0, stream>>>(indptr, blks);
  fill_fused<<<NE / 256, 256, 0, stream>>>(srcv, dstv, etime, tbl, indptr, cursor,
                                           es, aec1, aec2);
  ip_mfma<<<MB, 256, 0, stream>>>(x, w1t, ip_b1, ip_lnw, ip_lnb, w2t, ip_b2,
                                  pn_w, pn_b, h16);
  hp_mfma<<<MB, 256, 0, stream>>>(h16, g1wt, g1_as, g1_ad, hp16, asrc, adst);
  agg_k<0><<<NN / 4, 256, 0, stream>>>(indptr, es, aec1, asrc, adst, hp16, h16,
                                       g1_b, n1_w, n1_b, g16, nullptr);
  hp_mfma<<<MB, 256, 0, stream>>>(g16, g2wt, g2_as, g2_ad, hp16, asrc, adst);
  agg_k<1><<<NN / 4, 256, 0, stream>>>(indptr, es, aec2, asrc, adst, hp16, g16,
                                       g2_b, n2_w, n2_b, nullptr, (float*)d_out);
}

// Round 6
// 429.483 us; speedup vs baseline: 2.4886x; 1.0518x over previous
//
#include <hip/hip_runtime.h>

typedef unsigned short u16;
typedef __attribute__((ext_vector_type(8))) short bf8_t;   // 8 bf16 in 4 VGPRs
typedef __attribute__((ext_vector_type(4))) float f4_t;

constexpr int NN   = 50000;
constexpr int NE   = 800000;
constexpr int TBLN = 2048;

// ---------- helpers ----------
__device__ __forceinline__ float bf(const u16* p, int i) {
  return __uint_as_float(((unsigned)p[i]) << 16);
}
__device__ __forceinline__ u16 f2b(float f) {
  unsigned u = __float_as_uint(f);
  unsigned r = u + 0x7fffu + ((u >> 16) & 1u);  // RNE
  return (u16)(r >> 16);
}
__device__ __forceinline__ short f2bs(float f) {
  unsigned u = __float_as_uint(f);
  unsigned r = u + 0x7fffu + ((u >> 16) & 1u);
  return (short)(r >> 16);
}
__device__ __forceinline__ u16 f2h(float f) {
  _Float16 h = (_Float16)f;
  return __builtin_bit_cast(unsigned short, h);
}
__device__ __forceinline__ float h2f(u16 v) {
  _Float16 h = __builtin_bit_cast(_Float16, v);
  return (float)h;
}
__device__ __forceinline__ unsigned packh(float a, float b) {
  return (unsigned)f2h(a) | ((unsigned)f2h(b) << 16);
}
__device__ __forceinline__ float blo(unsigned u) { return __uint_as_float(u << 16); }
__device__ __forceinline__ float bhi(unsigned u) { return __uint_as_float(u & 0xffff0000u); }
__device__ __forceinline__ float wred64(float v) {
#pragma unroll
  for (int o = 32; o; o >>= 1) v += __shfl_xor(v, o);
  return v;
}
__device__ __forceinline__ bf8_t ldv(const u16* p) { return *(const bf8_t*)p; }
__device__ __forceinline__ bf8_t ldcvt(const float* p) {
  const float4 a = *(const float4*)p;
  const float4 b = *(const float4*)(p + 4);
  bf8_t r;
  r[0] = f2bs(a.x); r[1] = f2bs(a.y); r[2] = f2bs(a.z); r[3] = f2bs(a.w);
  r[4] = f2bs(b.x); r[5] = f2bs(b.y); r[6] = f2bs(b.z); r[7] = f2bs(b.w);
  return r;
}
__device__ __forceinline__ f4_t mfma16(bf8_t a, bf8_t b, f4_t c) {
  return __builtin_amdgcn_mfma_f32_16x16x32_bf16(a, b, c, 0, 0, 0);
}

// ---------- all weight transposes (fp32->bf16) in one launch ----------
__global__ void tcvt_all(const float* __restrict__ w1, const float* __restrict__ w2,
                         const float* __restrict__ gw1, const float* __restrict__ gw2,
                         u16* __restrict__ w1t, u16* __restrict__ w2t,
                         u16* __restrict__ g1wt, u16* __restrict__ g2wt) {
  int idx = blockIdx.x * 256 + threadIdx.x;  // 384 blocks -> 98304
  if (idx < 32768) {
    int r = idx >> 8, c = idx & 255;
    w1t[c * 128 + r] = f2b(w1[idx]);
  } else if (idx < 65536) {
    int k = idx - 32768;
    int r = k >> 7, c = k & 127;
    w2t[c * 256 + r] = f2b(w2[k]);
  } else if (idx < 81920) {
    int k = idx - 65536;
    int r = k >> 7, c = k & 127;
    g1wt[c * 128 + r] = f2b(gw1[k]);
  } else {
    int k = idx - 81920;
    int r = k >> 7, c = k & 127;
    g2wt[c * 128 + r] = f2b(gw2[k]);
  }
}

// ---------- fold edge-attention vectors ----------
__global__ void build_V(const float* __restrict__ ew1, const float* __restrict__ ate1,
                        const float* __restrict__ ew2, const float* __restrict__ ate2,
                        float* __restrict__ V) {
  const int t = threadIdx.x;
#pragma unroll
  for (int rep = 0; rep < 2; ++rep) {
    int idx = t + rep * 256;
    int k = idx >> 2, hd = idx & 3;
    float s1 = 0.f, s2 = 0.f;
    for (int c = 0; c < 32; ++c) {
      s1 += ew1[k * 128 + hd * 32 + c] * ate1[hd * 32 + c];
      s2 += ew2[k * 128 + hd * 32 + c] * ate2[hd * 32 + c];
    }
    V[k * 8 + hd] = s1;
    V[k * 8 + 4 + hd] = s2;
  }
}

// ---------- tabulate a_edge(t) ----------
__global__ __launch_bounds__(128) void build_table(
    const float* __restrict__ taw1, const float* __restrict__ tab1,
    const float* __restrict__ talnw, const float* __restrict__ talnb,
    const float* __restrict__ taw2, const float* __restrict__ tab2,
    const float* __restrict__ V, float* __restrict__ tbl) {
  const int j = threadIdx.x;
  const int wv = j >> 6, ln = j & 63;
  const float t = (float)blockIdx.x / (float)(TBLN - 1);
  __shared__ float part[4];
  __shared__ float ush[128];
  __shared__ float pacc[16];
  float v = t * taw1[j] + tab1[j];
  float s = wred64(v), sq = wred64(v * v);
  if (ln == 0) { part[wv * 2] = s; part[wv * 2 + 1] = sq; }
  __syncthreads();
  float S = part[0] + part[2], SQ = part[1] + part[3];
  float mu = S * (1.f / 128.f);
  float var = SQ * (1.f / 128.f) - mu * mu;
  float rstd = rsqrtf(var + 1e-5f);
  float u = fmaxf((v - mu) * rstd * talnw[j] + talnb[j], 0.f);
  ush[j] = u;
  __syncthreads();
  float acc = 0.f;
  for (int k = 0; k < 128; ++k) acc += ush[k] * taw2[k * 128 + j];
  float w = tanhf(acc + tab2[j]);
  w = fminf(fmaxf(w, -3.f), 3.f);
#pragma unroll
  for (int p = 0; p < 8; ++p) {
    float z = wred64(w * V[j * 8 + p]);
    if (ln == 0) pacc[wv * 8 + p] = z;
  }
  __syncthreads();
  if (j < 8) tbl[blockIdx.x * 8 + j] = pacc[j] + pacc[8 + j];
}

// ---------- MFMA input projection: 32 rows/block ----------
__global__ __launch_bounds__(256) void ip_mfma(
    const float* __restrict__ x, const u16* __restrict__ w1t,
    const float* __restrict__ b1, const float* __restrict__ ln1w,
    const float* __restrict__ ln1b, const u16* __restrict__ w2t,
    const float* __restrict__ b2, const float* __restrict__ pnw,
    const float* __restrict__ pnb, u16* __restrict__ h16) {
  __shared__ char smem[50176];
  float* h1f = (float*)smem;              // [32][260] fp32
  u16* h1n = (u16*)(smem + 33280);        // [32][264] bf16
  u16* h2n = h1n;                         // alias, reused after GEMM2

  const int t = threadIdx.x;
  const int w = t >> 6, lane = t & 63, q = lane >> 4, l15 = lane & 15;
  const int rowbase = blockIdx.x * 32;

  // GEMM1: [32,128] @ [128,256]
  f4_t acc[2][4];
#pragma unroll
  for (int mt = 0; mt < 2; ++mt)
#pragma unroll
    for (int nt = 0; nt < 4; ++nt) acc[mt][nt] = (f4_t){0.f, 0.f, 0.f, 0.f};
#pragma unroll
  for (int kst = 0; kst < 4; ++kst) {
    int k0 = kst * 32 + q * 8;
    int r0 = rowbase + l15;      if (r0 > NN - 1) r0 = NN - 1;
    int r1 = rowbase + 16 + l15; if (r1 > NN - 1) r1 = NN - 1;
    bf8_t a0 = ldcvt(x + r0 * 128 + k0);
    bf8_t a1 = ldcvt(x + r1 * 128 + k0);
#pragma unroll
    for (int nt = 0; nt < 4; ++nt) {
      int n = w * 64 + nt * 16 + l15;
      bf8_t b = ldv(w1t + n * 128 + k0);
      acc[0][nt] = mfma16(a0, b, acc[0][nt]);
      acc[1][nt] = mfma16(a1, b, acc[1][nt]);
    }
  }
#pragma unroll
  for (int mt = 0; mt < 2; ++mt)
#pragma unroll
    for (int nt = 0; nt < 4; ++nt) {
      int col = w * 64 + nt * 16 + l15;
      float bb = b1[col];
#pragma unroll
      for (int r = 0; r < 4; ++r) {
        int row = mt * 16 + q * 4 + r;
        h1f[row * 260 + col] = fmaxf(acc[mt][nt][r] + bb, 0.f);
      }
    }
  __syncthreads();
  // LN over 256 cols
  {
    const int row = t >> 3, sub = t & 7;
    const float* rp = h1f + row * 260;
    float sum = 0.f, sq = 0.f;
#pragma unroll
    for (int i = 0; i < 32; ++i) {
      float v = rp[sub + 8 * i];
      sum += v; sq += v * v;
    }
#pragma unroll
    for (int o = 1; o < 8; o <<= 1) { sum += __shfl_xor(sum, o); sq += __shfl_xor(sq, o); }
    float mu = sum * (1.f / 256.f);
    float var = sq * (1.f / 256.f) - mu * mu;
    float rstd = rsqrtf(var + 1e-5f);
#pragma unroll
    for (int i = 0; i < 32; ++i) {
      int c = sub + 8 * i;
      float v = (rp[c] - mu) * rstd * ln1w[c] + ln1b[c];
      h1n[row * 264 + c] = f2b(v);
    }
  }
  __syncthreads();
  // GEMM2: [32,256] @ [256,128]
  f4_t acc2[2][2];
#pragma unroll
  for (int mt = 0; mt < 2; ++mt)
#pragma unroll
    for (int nt = 0; nt < 2; ++nt) acc2[mt][nt] = (f4_t){0.f, 0.f, 0.f, 0.f};
#pragma unroll
  for (int kst = 0; kst < 8; ++kst) {
    int k0 = kst * 32 + q * 8;
    bf8_t a0 = ldv(h1n + (l15) * 264 + k0);
    bf8_t a1 = ldv(h1n + (16 + l15) * 264 + k0);
#pragma unroll
    for (int nt = 0; nt < 2; ++nt) {
      int n = w * 32 + nt * 16 + l15;
      bf8_t b = ldv(w2t + n * 256 + k0);
      acc2[0][nt] = mfma16(a0, b, acc2[0][nt]);
      acc2[1][nt] = mfma16(a1, b, acc2[1][nt]);
    }
  }
  __syncthreads();
#pragma unroll
  for (int mt = 0; mt < 2; ++mt)
#pragma unroll
    for (int nt = 0; nt < 2; ++nt) {
      int col = w * 32 + nt * 16 + l15;
      float bb = b2[col];
#pragma unroll
      for (int r = 0; r < 4; ++r) {
        int row = mt * 16 + q * 4 + r;
        h1f[row * 132 + col] = acc2[mt][nt][r] + bb;
      }
    }
  __syncthreads();
  // LN over 128 + relu + clip -> h2n (bf16)
  {
    const int row = t >> 3, sub = t & 7;
    const float* rp = h1f + row * 132;
    float sum = 0.f, sq = 0.f;
#pragma unroll
    for (int i = 0; i < 16; ++i) {
      float v = rp[sub + 8 * i];
      sum += v; sq += v * v;
    }
#pragma unroll
    for (int o = 1; o < 8; o <<= 1) { sum += __shfl_xor(sum, o); sq += __shfl_xor(sq, o); }
    float mu = sum * (1.f / 128.f);
    float var = sq * (1.f / 128.f) - mu * mu;
    float rstd = rsqrtf(var + 1e-5f);
#pragma unroll
    for (int i = 0; i < 16; ++i) {
      int c = sub + 8 * i;
      float v = (rp[c] - mu) * rstd * pnw[c] + pnb[c];
      v = fminf(fmaxf(v, 0.f), 10.f);
      h2n[row * 128 + c] = f2b(v);
    }
  }
  __syncthreads();
  {
    const int row = t >> 3, cb = (t & 7) * 16;
    int rg = rowbase + row;
    if (rg < NN) {
      uint4 v0 = *(const uint4*)(h2n + row * 128 + cb);
      uint4 v1 = *(const uint4*)(h2n + row * 128 + cb + 8);
      *(uint4*)(h16 + rg * 128 + cb) = v0;
      *(uint4*)(h16 + rg * 128 + cb + 8) = v1;
    }
  }
}

// ---------- MFMA node projection + attention logits ----------
__global__ __launch_bounds__(256) void hp_mfma(
    const u16* __restrict__ feat16, const u16* __restrict__ wt,
    const float* __restrict__ attsrc, const float* __restrict__ attdst,
    u16* __restrict__ hp16, float* __restrict__ asrc, float* __restrict__ adst) {
  const int t = threadIdx.x;
  const int w = t >> 6, lane = t & 63, q = lane >> 4, l15 = lane & 15;
  const int rowbase = blockIdx.x * 32;
  f4_t acc[2][2];
#pragma unroll
  for (int mt = 0; mt < 2; ++mt)
#pragma unroll
    for (int nt = 0; nt < 2; ++nt) acc[mt][nt] = (f4_t){0.f, 0.f, 0.f, 0.f};
#pragma unroll
  for (int kst = 0; kst < 4; ++kst) {
    int k0 = kst * 32 + q * 8;
    int r0 = rowbase + l15;      if (r0 > NN - 1) r0 = NN - 1;
    int r1 = rowbase + 16 + l15; if (r1 > NN - 1) r1 = NN - 1;
    bf8_t a0 = ldv(feat16 + r0 * 128 + k0);
    bf8_t a1 = ldv(feat16 + r1 * 128 + k0);
#pragma unroll
    for (int nt = 0; nt < 2; ++nt) {
      int n = w * 32 + nt * 16 + l15;
      bf8_t b = ldv(wt + n * 128 + k0);
      acc[0][nt] = mfma16(a0, b, acc[0][nt]);
      acc[1][nt] = mfma16(a1, b, acc[1][nt]);
    }
  }
  float ps[2][4], pd[2][4];
#pragma unroll
  for (int mt = 0; mt < 2; ++mt)
#pragma unroll
    for (int r = 0; r < 4; ++r) { ps[mt][r] = 0.f; pd[mt][r] = 0.f; }
#pragma unroll
  for (int mt = 0; mt < 2; ++mt)
#pragma unroll
    for (int nt = 0; nt < 2; ++nt) {
      int col = w * 32 + nt * 16 + l15;
      float as = attsrc[col], ad = attdst[col];
#pragma unroll
      for (int r = 0; r < 4; ++r) {
        int row = mt * 16 + q * 4 + r;
        int rg = rowbase + row;
        float v = acc[mt][nt][r];
        if (rg < NN) hp16[(size_t)rg * 128 + col] = f2b(v);
        ps[mt][r] += v * as;
        pd[mt][r] += v * ad;
      }
    }
#pragma unroll
  for (int o = 1; o < 16; o <<= 1)
#pragma unroll
    for (int mt = 0; mt < 2; ++mt)
#pragma unroll
      for (int r = 0; r < 4; ++r) {
        ps[mt][r] += __shfl_xor(ps[mt][r], o);
        pd[mt][r] += __shfl_xor(pd[mt][r], o);
      }
  if (l15 == 0) {
#pragma unroll
    for (int mt = 0; mt < 2; ++mt)
#pragma unroll
      for (int r = 0; r < 4; ++r) {
        int rg = rowbase + mt * 16 + q * 4 + r;
        if (rg < NN) {
          asrc[rg * 4 + w] = ps[mt][r];
          adst[rg * 4 + w] = pd[mt][r];
        }
      }
  }
}

// ---------- deg histogram ----------
__global__ __launch_bounds__(256) void deg_k(const int* __restrict__ dstv,
                                             int* __restrict__ deg) {
  int e = blockIdx.x * 256 + threadIdx.x;
  if (e < NE) atomicAdd(&deg[dstv[e]], 1);
}

// ---------- scans ----------
__global__ __launch_bounds__(512) void scan1(const int* __restrict__ deg,
                                             int* __restrict__ indptr,
                                             int* __restrict__ blks) {
  const int t = threadIdx.x;
  const int i = blockIdx.x * 512 + t;
  int v = (i < NN) ? deg[i] : 0;
  const int lane = t & 63, wv = t >> 6;
  int x = v;
#pragma unroll
  for (int o = 1; o < 64; o <<= 1) {
    int y = __shfl_up(x, o);
    if (lane >= o) x += y;
  }
  __shared__ int ws[8];
  if (lane == 63) ws[wv] = x;
  __syncthreads();
  if (t < 8) {
    int y = ws[t];
#pragma unroll
    for (int o = 1; o < 8; o <<= 1) {
      int z = __shfl_up(y, o);
      if (t >= o) y += z;
    }
    ws[t] = y;
  }
  __syncthreads();
  int excl = wv ? ws[wv - 1] : 0;
  x += excl;
  if (i < NN) indptr[i + 1] = x;
  if (t == 511) blks[blockIdx.x] = x;
}
__global__ void scan2(int* __restrict__ blks, int nb) {
  const int t = threadIdx.x;
  int v = (t < nb) ? blks[t] : 0;
  const int lane = t & 63, wv = t >> 6;
  int x = v;
#pragma unroll
  for (int o = 1; o < 64; o <<= 1) {
    int y = __shfl_up(x, o);
    if (lane >= o) x += y;
  }
  __shared__ int ws[2];
  if (lane == 63) ws[wv] = x;
  __syncthreads();
  if (wv == 1) x += ws[0];
  if (t < nb) blks[t] = x - v;
}
__global__ __launch_bounds__(512) void scan3(int* __restrict__ indptr,
                                             const int* __restrict__ blks) {
  const int i = blockIdx.x * 512 + threadIdx.x;
  if (i < NN) indptr[i + 1] += blks[blockIdx.x];
  if (i == 0) indptr[0] = 0;
}

// ---------- fill CSR-ordered 32B edge records: {src, ae1[4]:fp16, ae2[4]:fp16} ----------
__global__ __launch_bounds__(256) void fill_fused(
    const int* __restrict__ srcv, const int* __restrict__ dstv,
    const float* __restrict__ etime, const float* __restrict__ tbl,
    const int* __restrict__ indptr, int* __restrict__ cursor,
    u16* __restrict__ recs) {
  const int e = blockIdx.x * 256 + threadIdx.x;
  if (e >= NE) return;
  int d = dstv[e];
  int p = atomicAdd(&cursor[d], 1);
  int pos = indptr[d] + p;
  float t = etime[e];
  t = fminf(fmaxf(t, 0.f), 1.f);
  float fpos = t * (float)(TBLN - 1);
  int i0 = (int)fpos;
  if (i0 > TBLN - 2) i0 = TBLN - 2;
  float fr = fpos - (float)i0;
  const float4* r = (const float4*)(tbl + i0 * 8);
  float4 a0 = r[0], a1 = r[1], b0 = r[2], b1 = r[3];
  float4 o1, o2;
  o1.x = a0.x + fr * (b0.x - a0.x); o1.y = a0.y + fr * (b0.y - a0.y);
  o1.z = a0.z + fr * (b0.z - a0.z); o1.w = a0.w + fr * (b0.w - a0.w);
  o2.x = a1.x + fr * (b1.x - a1.x); o2.y = a1.y + fr * (b1.y - a1.y);
  o2.z = a1.z + fr * (b1.z - a1.z); o2.w = a1.w + fr * (b1.w - a1.w);
  u16* rp = recs + (size_t)pos * 16;
  uint4 w;
  w.x = (unsigned)srcv[e];
  w.y = packh(o1.x, o1.y);
  w.z = packh(o1.z, o1.w);
  w.w = packh(o2.x, o2.y);
  *(uint4*)rp = w;
  *(unsigned*)(rp + 8) = packh(o2.z, o2.w);
}

// ---------- GAT aggregation: single pass, unnormalized accumulate ----------
template <int L, int FINAL>
__global__ __launch_bounds__(256) void agg_k(
    const int* __restrict__ indptr, const u16* __restrict__ recs,
    const float* __restrict__ asrc, const float* __restrict__ adst,
    const u16* __restrict__ hp16, const u16* __restrict__ feat16,
    const float* __restrict__ gbias, const float* __restrict__ lnw,
    const float* __restrict__ lnb, u16* __restrict__ gout16,
    float* __restrict__ out32) {
  const int wv = threadIdx.x >> 6, lane = threadIdx.x & 63;
  const int n = blockIdx.x * 4 + wv;
  if (n >= NN) return;
  const int s0 = indptr[n], s1 = indptr[n + 1];
  const int dg = s1 - s0;
  const int g = lane >> 4, sl = lane & 15, cb = sl * 8, hdB = sl >> 2;
  const float advB = adst[n * 4 + hdB];
  float ssp = 0.f, sap = 0.f;
  float acc[8];
#pragma unroll
  for (int i = 0; i < 8; ++i) acc[i] = 0.f;
  for (int base = s0; base < s1; base += 8) {
    int i0 = base + g, i1 = base + 4 + g;
    int j0 = i0 < s1 ? i0 : s1 - 1;
    int j1 = i1 < s1 ? i1 : s1 - 1;
    const u16* r0 = recs + j0 * 16;
    const u16* r1 = recs + j1 * 16;
    int sc0 = *(const int*)r0, sc1 = *(const int*)r1;
    float ae0 = h2f(r0[2 + 4 * L + hdB]);
    float ae1v = h2f(r1[2 + 4 * L + hdB]);
    float as0 = asrc[sc0 * 4 + hdB], as1 = asrc[sc1 * 4 + hdB];
    const uint4 row0 = *(const uint4*)(hp16 + sc0 * 128 + cb);
    const uint4 row1 = *(const uint4*)(hp16 + sc1 * 128 + cb);
    float l0 = as0 + advB + ae0; l0 = fmaxf(l0, 0.2f * l0);
    float l1 = as1 + advB + ae1v; l1 = fmaxf(l1, 0.2f * l1);
    float w0 = (i0 < s1) ? __expf(l0) : 0.f;
    float w1 = (i1 < s1) ? __expf(l1) : 0.f;
    ssp += w0 + w1;
    sap += ((i0 < s1) ? ae0 : 0.f) + ((i1 < s1) ? ae1v : 0.f);
    acc[0] += w0 * blo(row0.x) + w1 * blo(row1.x);
    acc[1] += w0 * bhi(row0.x) + w1 * bhi(row1.x);
    acc[2] += w0 * blo(row0.y) + w1 * blo(row1.y);
    acc[3] += w0 * bhi(row0.y) + w1 * bhi(row1.y);
    acc[4] += w0 * blo(row0.z) + w1 * blo(row1.z);
    acc[5] += w0 * bhi(row0.z) + w1 * bhi(row1.z);
    acc[6] += w0 * blo(row0.w) + w1 * blo(row1.w);
    acc[7] += w0 * bhi(row0.w) + w1 * bhi(row1.w);
  }
  // reduce across the 4 edge-groups
#pragma unroll
  for (int i = 0; i < 8; ++i) {
    acc[i] += __shfl_xor(acc[i], 16);
    acc[i] += __shfl_xor(acc[i], 32);
  }
  ssp += __shfl_xor(ssp, 16); ssp += __shfl_xor(ssp, 32);
  sap += __shfl_xor(sap, 16); sap += __shfl_xor(sap, 32);
  // self-loop (fill_value='mean' fold) + normalization
  const float degf = (float)(dg > 0 ? dg : 1);
  float asnB = asrc[n * 4 + hdB];
  float la = asnB + advB + sap / degf;
  la = fmaxf(la, 0.2f * la);
  float wsf = __expf(la);
  float inv = 1.f / (ssp + wsf + 1e-16f);
  // epilogue
  const uint4 rs4 = *(const uint4*)(hp16 + (size_t)n * 128 + cb);
  const uint4 rr4 = *(const uint4*)(feat16 + (size_t)n * 128 + cb);
  const float4 gb0 = *(const float4*)(gbias + cb);
  const float4 gb1 = *(const float4*)(gbias + cb + 4);
  float v[8];
  v[0] = (acc[0] + wsf * blo(rs4.x)) * inv + gb0.x + blo(rr4.x);
  v[1] = (acc[1] + wsf * bhi(rs4.x)) * inv + gb0.y + bhi(rr4.x);
  v[2] = (acc[2] + wsf * blo(rs4.y)) * inv + gb0.z + blo(rr4.y);
  v[3] = (acc[3] + wsf * bhi(rs4.y)) * inv + gb0.w + bhi(rr4.y);
  v[4] = (acc[4] + wsf * blo(rs4.z)) * inv + gb1.x + blo(rr4.z);
  v[5] = (acc[5] + wsf * bhi(rs4.z)) * inv + gb1.y + bhi(rr4.z);
  v[6] = (acc[6] + wsf * blo(rs4.w)) * inv + gb1.z + blo(rr4.w);
  v[7] = (acc[7] + wsf * bhi(rs4.w)) * inv + gb1.w + bhi(rr4.w);
  float sum = 0.f, sq = 0.f;
#pragma unroll
  for (int i = 0; i < 8; ++i) {
    v[i] = fminf(fmaxf(v[i], -10.f), 10.f);
    sum += v[i]; sq += v[i] * v[i];
  }
#pragma unroll
  for (int o = 1; o < 16; o <<= 1) {
    sum += __shfl_xor(sum, o);
    sq += __shfl_xor(sq, o);
  }
  float mu = sum * (1.f / 128.f);
  float var = sq * (1.f / 128.f) - mu * mu;
  float rstd = rsqrtf(var + 1e-5f);
  const float4 lw0 = *(const float4*)(lnw + cb);
  const float4 lw1 = *(const float4*)(lnw + cb + 4);
  const float4 lb0 = *(const float4*)(lnb + cb);
  const float4 lb1 = *(const float4*)(lnb + cb + 4);
  float y[8];
  y[0] = (v[0] - mu) * rstd * lw0.x + lb0.x;
  y[1] = (v[1] - mu) * rstd * lw0.y + lb0.y;
  y[2] = (v[2] - mu) * rstd * lw0.z + lb0.z;
  y[3] = (v[3] - mu) * rstd * lw0.w + lb0.w;
  y[4] = (v[4] - mu) * rstd * lw1.x + lb1.x;
  y[5] = (v[5] - mu) * rstd * lw1.y + lb1.y;
  y[6] = (v[6] - mu) * rstd * lw1.z + lb1.z;
  y[7] = (v[7] - mu) * rstd * lw1.w + lb1.w;
#pragma unroll
  for (int i = 0; i < 8; ++i) y[i] = y[i] > 0.f ? y[i] : expm1f(y[i]);
  if (g == 0) {
    if (FINAL) {
      float4 o0 = {y[0], y[1], y[2], y[3]};
      float4 o1 = {y[4], y[5], y[6], y[7]};
      *(float4*)(out32 + (size_t)n * 128 + cb) = o0;
      *(float4*)(out32 + (size_t)n * 128 + cb + 4) = o1;
    } else {
      uint4 o;
      o.x = (unsigned)f2b(y[0]) | ((unsigned)f2b(y[1]) << 16);
      o.y = (unsigned)f2b(y[2]) | ((unsigned)f2b(y[3]) << 16);
      o.z = (unsigned)f2b(y[4]) | ((unsigned)f2b(y[5]) << 16);
      o.w = (unsigned)f2b(y[6]) | ((unsigned)f2b(y[7]) << 16);
      *(uint4*)(gout16 + (size_t)n * 128 + cb) = o;
    }
  }
}

// ---------- launch ----------
extern "C" void kernel_launch(void* const* d_in, const int* in_sizes, int n_in,
                              void* d_out, int out_size, void* d_ws, size_t ws_size,
                              hipStream_t stream) {
  const float* x      = (const float*)d_in[0];
  const float* etime  = (const float*)d_in[1];
  const float* ip_w1  = (const float*)d_in[2];
  const float* ip_b1  = (const float*)d_in[3];
  const float* ip_lnw = (const float*)d_in[4];
  const float* ip_lnb = (const float*)d_in[5];
  const float* ip_w2  = (const float*)d_in[6];
  const float* ip_b2  = (const float*)d_in[7];
  const float* pn_w   = (const float*)d_in[8];
  const float* pn_b   = (const float*)d_in[9];
  const float* ta_w1  = (const float*)d_in[10];
  const float* ta_b1  = (const float*)d_in[11];
  const float* ta_lnw = (const float*)d_in[12];
  const float* ta_lnb = (const float*)d_in[13];
  const float* ta_w2  = (const float*)d_in[14];
  const float* ta_b2  = (const float*)d_in[15];
  const float* g1_w   = (const float*)d_in[16];
  const float* g1_as  = (const float*)d_in[17];
  const float* g1_ad  = (const float*)d_in[18];
  const float* g1_ew  = (const float*)d_in[19];
  const float* g1_ae  = (const float*)d_in[20];
  const float* g1_b   = (const float*)d_in[21];
  const float* g2_w   = (const float*)d_in[22];
  const float* g2_as  = (const float*)d_in[23];
  const float* g2_ad  = (const float*)d_in[24];
  const float* g2_ew  = (const float*)d_in[25];
  const float* g2_ae  = (const float*)d_in[26];
  const float* g2_b   = (const float*)d_in[27];
  const float* n1_w   = (const float*)d_in[28];
  const float* n1_b   = (const float*)d_in[29];
  const float* n2_w   = (const float*)d_in[30];
  const float* n2_b   = (const float*)d_in[31];
  const int* eidx     = (const int*)d_in[32];
  const int* srcv = eidx;
  const int* dstv = eidx + NE;

  char* p = (char*)d_ws;
  auto carve = [&](size_t bytes) -> char* {
    char* r = p;
    p += (bytes + 255) & ~(size_t)255;
    return r;
  };
  u16*   h16    = (u16*)carve((size_t)NN * 128 * 2);
  u16*   g16    = (u16*)carve((size_t)NN * 128 * 2);
  u16*   hp16   = (u16*)carve((size_t)NN * 128 * 2);
  float* asrc   = (float*)carve((size_t)NN * 4 * 4);
  float* adst   = (float*)carve((size_t)NN * 4 * 4);
  u16*   recs   = (u16*)carve((size_t)NE * 32);
  int*   deg    = (int*)carve((size_t)NN * 4);
  int*   indptr = (int*)carve((size_t)(NN + 1) * 4);
  int*   cursor = (int*)carve((size_t)NN * 4);
  int*   blks   = (int*)carve(512 * 4);
  float* V      = (float*)carve(128 * 8 * 4);
  float* tbl    = (float*)carve((size_t)TBLN * 8 * 4);
  u16*   w1t    = (u16*)carve(128 * 256 * 2);
  u16*   w2t    = (u16*)carve(256 * 128 * 2);
  u16*   g1wt   = (u16*)carve(128 * 128 * 2);
  u16*   g2wt   = (u16*)carve(128 * 128 * 2);

  hipMemsetAsync(deg, 0, (size_t)NN * 4, stream);
  hipMemsetAsync(cursor, 0, (size_t)NN * 4, stream);

  const int SCB = (NN + 511) / 512;
  const int MB = (NN + 31) / 32;  // 1563

  build_V<<<1, 256, 0, stream>>>(g1_ew, g1_ae, g2_ew, g2_ae, V);
  build_table<<<TBLN, 128, 0, stream>>>(ta_w1, ta_b1, ta_lnw, ta_lnb, ta_w2, ta_b2, V, tbl);
  tcvt_all<<<384, 256, 0, stream>>>(ip_w1, ip_w2, g1_w, g2_w, w1t, w2t, g1wt, g2wt);
  deg_k<<<NE / 256, 256, 0, stream>>>(dstv, deg);
  scan1<<<SCB, 512, 0, stream>>>(deg, indptr, blks);
  scan2<<<1, 128, 0, stream>>>(blks, SCB);
  scan3<<<SCB, 512, 0, stream>>>(indptr, blks);
  fill_fused<<<NE / 256, 256, 0, stream>>>(srcv, dstv, etime, tbl, indptr, cursor, recs);
  ip_mfma<<<MB, 256, 0, stream>>>(x, w1t, ip_b1, ip_lnw, ip_lnb, w2t, ip_b2,
                                  pn_w, pn_b, h16);
  hp_mfma<<<MB, 256, 0, stream>>>(h16, g1wt, g1_as, g1_ad, hp16, asrc, adst);
  agg_k<0, 0><<<NN / 4 + 1, 256, 0, stream>>>(indptr, recs, asrc, adst, hp16, h16,
                                              g1_b, n1_w, n1_b, g16, nullptr);
  hp_mfma<<<MB, 256, 0, stream>>>(g16, g2wt, g2_as, g2_ad, hp16, asrc, adst);
  agg_k<1, 1><<<NN / 4 + 1, 256, 0, stream>>>(indptr, recs, asrc, adst, hp16, g16,
                                              g2_b, n2_w, n2_b, nullptr, (float*)d_out);
}